// Round 14
// baseline (382.939 us; speedup 1.0000x reference)
//
#include <hip/hip_runtime.h>
#include <stdint.h>

#define T_TOK 32768
#define H_DIM 576
#define I_DIM 512
#define NEXP 8
#define WELEM 294912  // 576*512 elements per expert weight matrix

#define NB_RT 512     // prep: router blocks (64 tokens each)
#define NB_CW 7776    // prep: weight-transpose blocks
#define NB_GU_R 2112  // routed gateup blocks (merged, 528 mb x 4 nb)
#define NB_GU_S 1024  // shared gateup blocks (256 mb x 4 nb)

typedef __attribute__((ext_vector_type(8))) short short8;
typedef __attribute__((ext_vector_type(4))) float f32x4;
typedef __attribute__((ext_vector_type(4))) float f4;
typedef __attribute__((ext_vector_type(4))) unsigned short u16x4;

__device__ __forceinline__ unsigned short f2bf(float f) {
  union { float f; unsigned u; } v; v.f = f;
  unsigned r = (v.u + 0x7fffu + ((v.u >> 16) & 1u)) >> 16;
  return (unsigned short)r;
}

__device__ __forceinline__ void gl16(const void* g, void* l) {
  __builtin_amdgcn_global_load_lds(
      (const __attribute__((address_space(1))) unsigned*)g,
      (__attribute__((address_space(3))) unsigned*)l, 16, 0, 0);
}

// ============ packed prep: router+cvt_x (512 blks) || weight transposes ======
__global__ __launch_bounds__(256) void prep_k(
    const float* __restrict__ x, unsigned short* __restrict__ xb,
    const float* __restrict__ rw, const float* __restrict__ rb,
    int* __restrict__ tki, float* __restrict__ tkw, int* __restrict__ counts,
    const float* __restrict__ sgw, const float* __restrict__ suw,
    const float* __restrict__ rgw, const float* __restrict__ ruw,
    const float* __restrict__ sdw, const float* __restrict__ rdw,
    unsigned short* __restrict__ wsg, unsigned short* __restrict__ wsu,
    unsigned short* __restrict__ wrg, unsigned short* __restrict__ wru,
    unsigned short* __restrict__ wsd, unsigned short* __restrict__ wrd) {
  __shared__ __align__(16) char smem[29312];
  int b = blockIdx.x, tid = threadIdx.x;
  if (b < NB_RT) {
    float* lrw = (float*)smem;                         // 18432 B
    float (*tile)[68] = (float(*)[68])(smem + 18432);  // 8704 B
    float (*red)[8] = (float(*)[8])(smem + 27136);     // 2048 B
    int* hist = (int*)(smem + 29184);                  // 64 B
    for (int i = tid; i < 1152; i += 256)
      *(f4*)&lrw[i * 4] = *(const f4*)&rw[i * 4];
    if (tid < 16) hist[tid] = 0;
    int t0 = b * 64;
    float acc[NEXP] = {};
    for (int c = 0; c < 18; c++) {
      __syncthreads();
#pragma unroll
      for (int k = 0; k < 2; k++) {
        int f = tid + k * 256;
        int rgrp = f >> 8, fl = f & 255;
        int tl2 = fl >> 2, seg = fl & 3;
        int h = rgrp * 288 + c * 16 + seg * 4;
        size_t gi = (size_t)(t0 + tl2) * H_DIM + h;
        f4 v = *(const f4*)(x + gi);
        u16x4 o;
        o.x = f2bf(v.x); o.y = f2bf(v.y); o.z = f2bf(v.z); o.w = f2bf(v.w);
        *(u16x4*)(xb + gi) = o;
        int row = rgrp * 16 + seg * 4;
        tile[row + 0][tl2] = v.x; tile[row + 1][tl2] = v.y;
        tile[row + 2][tl2] = v.z; tile[row + 3][tl2] = v.w;
      }
      __syncthreads();
      if (tid < 128) {
        int half = tid >> 6, tl = tid & 63;
        int hbase = half * 288 + c * 16;
        int rbase = half * 16;
#pragma unroll
        for (int hh = 0; hh < 16; hh++) {
          float xv = tile[rbase + hh][tl];
          f4 w0 = *(const f4*)&lrw[(hbase + hh) * 8];
          f4 w1 = *(const f4*)&lrw[(hbase + hh) * 8 + 4];
          acc[0] += xv * w0.x; acc[1] += xv * w0.y;
          acc[2] += xv * w0.z; acc[3] += xv * w0.w;
          acc[4] += xv * w1.x; acc[5] += xv * w1.y;
          acc[6] += xv * w1.z; acc[7] += xv * w1.w;
        }
      }
    }
    if (tid >= 64 && tid < 128) {
      int tl = tid & 63;
#pragma unroll
      for (int e = 0; e < NEXP; e++) red[tl][e] = acc[e];
    }
    __syncthreads();
    if (tid < 64) {
      int t = t0 + tid;
      float l[NEXP];
#pragma unroll
      for (int e = 0; e < NEXP; e++) l[e] = acc[e] + red[tid][e] + rb[e];
      int e0 = 0;
#pragma unroll
      for (int e = 1; e < NEXP; e++) if (l[e] > l[e0]) e0 = e;
      int e1 = -1;
#pragma unroll
      for (int e = 0; e < NEXP; e++) {
        if (e == e0) continue;
        if (e1 < 0 || l[e] > l[e1]) e1 = e;
      }
      float w0 = 1.f / (1.f + __expf(l[e1] - l[e0]));
      tki[t * 2] = e0; tki[t * 2 + 1] = e1;
      tkw[t * 2] = w0; tkw[t * 2 + 1] = 1.f - w0;
      atomicAdd(&hist[e0], 1);
      atomicAdd(&hist[8 + e1], 1);
    }
    __syncthreads();
    if (tid < 16) atomicAdd(&counts[tid * 32], hist[tid]);
  } else {
    float (*tile)[33] = (float(*)[33])smem;
    int b0 = b - NB_RT;
    const float* src; unsigned short* dst;
    int C, bx, by;
    if (b0 < 5184) {
      int z = b0 / 288, r = b0 % 288;
      bx = r & 15; by = r >> 4; C = 512;
      if (z == 0)      { src = sgw;                            dst = wsg; }
      else if (z == 1) { src = suw;                            dst = wsu; }
      else if (z < 10) { src = rgw + (size_t)(z - 2) * WELEM;  dst = wrg + (size_t)(z - 2) * WELEM; }
      else             { src = ruw + (size_t)(z - 10) * WELEM; dst = wru + (size_t)(z - 10) * WELEM; }
    } else {
      int b2 = b0 - 5184;
      int z = b2 / 288, r = b2 % 288;
      bx = r % 18; by = r / 18; C = 576;
      src = (z == 0) ? sdw : rdw + (size_t)(z - 1) * WELEM;
      dst = (z == 0) ? wsd : wrd + (size_t)(z - 1) * WELEM;
    }
    int R = 1088 - C;
    int tx = tid & 31, ty = tid >> 5;
    int r0 = by * 32, c0 = bx * 32;
    for (int i = ty; i < 32; i += 8)
      tile[i][tx] = src[(size_t)(r0 + i) * C + c0 + tx];
    __syncthreads();
    for (int i = ty; i < 32; i += 8)
      dst[(size_t)(c0 + i) * R + r0 + tx] = f2bf(tile[tx][i]);
  }
}

// ============ scatter with fused offsets scan ================================
__global__ __launch_bounds__(256) void scatter_k(
    const int* __restrict__ tki, const float* __restrict__ tkw,
    const int* __restrict__ counts, int* __restrict__ cursor /*stride 32*/,
    int* __restrict__ etok, float* __restrict__ ew,
    int* __restrict__ offs16g, int* __restrict__ pcnt16g,
    int* __restrict__ pinfog) {
  __shared__ int soffs[16], hist[16], base[16], lcur[16];
  int tid = threadIdx.x;
  if (tid == 0) {
    int o = 0, p0 = 0;
    for (int s = 0; s < 16; s++) {
      int c = counts[s * 32];
      int pc = (c + 127) & ~127;
      soffs[s] = o;
      if (blockIdx.x == 0) { offs16g[s] = o; pcnt16g[s] = pc; }
      o += pc;
      if (s == 7) p0 = o;
    }
    if (blockIdx.x == 0) { pinfog[0] = p0; pinfog[1] = o - p0; }
  }
  if (tid < 16) { hist[tid] = 0; lcur[tid] = 0; }
  __syncthreads();
  int t = blockIdx.x * 256 + tid;
  int s0 = tki[t * 2], s1 = 8 + tki[t * 2 + 1];
  atomicAdd(&hist[s0], 1);
  atomicAdd(&hist[s1], 1);
  __syncthreads();
  if (tid < 16) base[tid] = atomicAdd(&cursor[tid * 32], hist[tid]);
  __syncthreads();
#pragma unroll
  for (int k = 0; k < 2; k++) {
    int s = (k == 0) ? s0 : s1;
    int r = atomicAdd(&lcur[s], 1);
    int slot = soffs[s] + base[s] + r;
    etok[slot] = t;
    ew[slot] = tkw[t * 2 + k];
  }
}

// ---------------- fused gate/up GEMM + silu, runtime routed/shared -----------
// Routed blocks fold routing weight w into h: h = bf16(w * silu(g) * u).
// ew reads are VECTORIZED (4 x f4) and HOISTED before the K-loop so their
// latency hides under the GEMM (r13 lesson: 16 scalar epilogue loads = +12us).
__global__ __launch_bounds__(512, 2) void gateup_k(
    const unsigned short* __restrict__ xb,
    const unsigned short* __restrict__ wg_s, const unsigned short* __restrict__ wu_s,
    const unsigned short* __restrict__ wg_r, const unsigned short* __restrict__ wu_r,
    unsigned short* __restrict__ h_s, unsigned short* __restrict__ h_r,
    const int* __restrict__ etok, const float* __restrict__ ew,
    const int* __restrict__ offs16, const int* __restrict__ pcnt16,
    const int* __restrict__ pinfo,
    int nrg, int p, int merged, int mchunk_r) {
  int bid = blockIdx.x;
  bool routed = bid < nrg;
  int mb, nb;
  if (routed) {
    int xcd = bid & 7, l = bid >> 3;
    mb = xcd * mchunk_r + (l >> 2);
    nb = l & 3;
    int nrows = merged ? pinfo[0] + pinfo[1] : pinfo[p];
    if (mb * 128 >= nrows) return;
  } else {
    int b2 = bid - nrg;
    int xcd = b2 & 7, l = b2 >> 3;
    mb = xcd * 32 + (l >> 2);
    nb = l & 3;
  }
  __shared__ unsigned short As[128 * 32];
  __shared__ unsigned short Bg[128 * 32];
  __shared__ unsigned short Bu[128 * 32];
  int t = threadIdx.x;
  int wv = t >> 6, lane = t & 63;
  int ar = t >> 2, seg = t & 3;
  int sg = seg ^ ((ar >> 1) & 3);
  int m0 = mb * 128 + ar;
  int tok0;
  const unsigned short *wgp, *wup;
  unsigned short* hp;
  const float* ewp = nullptr;
  if (routed) {
    int rl = (!merged && p) ? pinfo[0] : 0;
    int g = rl + m0;
    int s = 0;
#pragma unroll
    for (int i = 0; i < 15; i++) s += (g >= offs16[i] + pcnt16[i]) ? 1 : 0;
    int e = s & 7;
    tok0 = etok[g];
    if (tok0 < 0) tok0 = 0;
    wgp = wg_r + (size_t)e * WELEM;
    wup = wu_r + (size_t)e * WELEM;
    hp = h_r;
    ewp = ew + rl;
  } else {
    tok0 = m0;
    wgp = wg_s;
    wup = wu_s;
    hp = h_s;
  }
  const unsigned short* ga = xb + (size_t)tok0 * H_DIM + sg * 8;
  int n0 = nb * 128 + ar;
  const unsigned short* gg = wgp + (size_t)n0 * H_DIM + sg * 8;
  const unsigned short* gu = wup + (size_t)n0 * H_DIM + sg * 8;
  char* lA = (char*)As + wv * 1024;
  char* lG = (char*)Bg + wv * 1024;
  char* lU = (char*)Bu + wv * 1024;
  int fr = lane & 15, fq = lane >> 4;
  int wm = (wv >> 2) * 64, wn = (wv & 3) * 32;
  // hoisted + vectorized routing weights (latency hidden by the K-loop)
  f4 ew4[4];
  if (routed) {
#pragma unroll
    for (int i = 0; i < 4; i++)
      ew4[i] = *(const f4*)&ewp[mb * 128 + wm + i * 16 + fq * 4];
  }
  f32x4 accg[4][2] = {};
  f32x4 accu[4][2] = {};
  for (int k0 = 0; k0 < H_DIM; k0 += 32) {
    gl16(ga + k0, lA);
    gl16(gg + k0, lG);
    gl16(gu + k0, lU);
    __syncthreads();
    short8 a[4], g[2], u[2];
#pragma unroll
    for (int i = 0; i < 4; i++) {
      int r = wm + i * 16 + fr;
      a[i] = *(const short8*)&As[r * 32 + (fq ^ ((r >> 1) & 3)) * 8];
    }
#pragma unroll
    for (int j = 0; j < 2; j++) {
      int r = wn + j * 16 + fr;
      int sw = (fq ^ ((r >> 1) & 3)) * 8;
      g[j] = *(const short8*)&Bg[r * 32 + sw];
      u[j] = *(const short8*)&Bu[r * 32 + sw];
    }
#pragma unroll
    for (int i = 0; i < 4; i++)
#pragma unroll
      for (int j = 0; j < 2; j++) {
        accg[i][j] = __builtin_amdgcn_mfma_f32_16x16x32_bf16(a[i], g[j], accg[i][j], 0, 0, 0);
        accu[i][j] = __builtin_amdgcn_mfma_f32_16x16x32_bf16(a[i], u[j], accu[i][j], 0, 0, 0);
      }
    __syncthreads();
  }
#pragma unroll
  for (int i = 0; i < 4; i++)
#pragma unroll
    for (int j = 0; j < 2; j++)
#pragma unroll
      for (int r = 0; r < 4; r++) {
        int row = mb * 128 + wm + i * 16 + fq * 4 + r;
        int col = nb * 128 + wn + j * 16 + fr;
        float gv = accg[i][j][r], uv = accu[i][j][r];
        float hv = (gv / (1.f + __expf(-gv))) * uv;
        if (routed) hv *= ew4[i][r];
        hp[(size_t)row * I_DIM + col] = f2bf(hv);
      }
}

// ---------------- down GEMM: 128x192 tile ------------------------------------
// MODE 0: shared store. MODE 1: routed RMW out += v (h pre-scaled by w).
// MODE 2: fused shared+primary -- TWO K-loops into one accumulator:
//         acc = hS[tok]*wsd + h[slot]*wrd[e]; single STORE of out[tok].
#define DK_KLOOP(GA, GB0, GB1)                                              \
  for (int k0 = 0; k0 < I_DIM; k0 += 32) {                                  \
    gl16((GA) + k0, (char*)Ab + wb);                                        \
    gl16((GB0) + k0, (char*)Bb + wb);                                       \
    if (t < 256) gl16((GB1) + k0, (char*)Bb + 8192 + wb);                   \
    __syncthreads();                                                        \
    short8 a[4], b2[3];                                                     \
    _Pragma("unroll") for (int i = 0; i < 4; i++) {                         \
      int r = wm + i * 16 + fr;                                             \
      a[i] = *(const short8*)&Ab[r * 32 + (fq ^ ((r >> 1) & 3)) * 8];       \
    }                                                                       \
    _Pragma("unroll") for (int j = 0; j < 3; j++) {                         \
      int r = wn + j * 16 + fr;                                             \
      b2[j] = *(const short8*)&Bb[r * 32 + (fq ^ ((r >> 1) & 3)) * 8];      \
    }                                                                       \
    _Pragma("unroll") for (int i = 0; i < 4; i++)                           \
      _Pragma("unroll") for (int j = 0; j < 3; j++)                         \
        acc[i][j] = __builtin_amdgcn_mfma_f32_16x16x32_bf16(a[i], b2[j],    \
                                                            acc[i][j], 0, 0, 0); \
    __syncthreads();                                                        \
  }

template <int MODE>
__global__ __launch_bounds__(512, 2) void down_k(
    const unsigned short* __restrict__ hbuf, const unsigned short* __restrict__ hS,
    const unsigned short* __restrict__ wd, const unsigned short* __restrict__ wsd,
    float* __restrict__ out, const int* __restrict__ etok,
    const int* __restrict__ offs16, const int* __restrict__ pcnt16,
    const int* __restrict__ pinfo, int p, int merged, int mchunk) {
  int bid = blockIdx.x;
  int xcd = bid & 7, l = bid >> 3;
  int mb = xcd * mchunk + l / 3;
  int nb = l % 3;
  int nrows = (MODE == 0) ? T_TOK : pinfo[p];
  if (mb * 128 >= nrows) return;
  int row_lo = (MODE == 1 && p == 1) ? pinfo[0] : 0;
  int hrow_lo = (MODE == 1 && merged) ? row_lo : 0;
  __shared__ char lds[24576];  // A 8KB | B 12KB ; epilogue fp32 32x192
  unsigned short* Ab = (unsigned short*)lds;
  unsigned short* Bb = (unsigned short*)(lds + 8192);
  int t = threadIdx.x;
  int wv = t >> 6, lane = t & 63;
  int ar = t >> 2, seg = t & 3;
  int sg = seg ^ ((ar >> 1) & 3);
  int e = 0, tokA = 0;
  if (MODE >= 1) {
    int g = row_lo + mb * 128 + ar;
    int s = 0;
#pragma unroll
    for (int i = 0; i < 15; i++) s += (g >= offs16[i] + pcnt16[i]) ? 1 : 0;
    e = s & 7;
    if (MODE == 2) {
      int tk = etok[g];
      tokA = (tk < 0) ? 0 : tk;
    }
  }
  const unsigned short* gaR = hbuf + (size_t)(hrow_lo + mb * 128 + ar) * I_DIM + sg * 8;
  int n00 = nb * 192 + ar;
  const unsigned short* gbR = wd + (size_t)e * WELEM + (size_t)n00 * I_DIM + sg * 8;
  const unsigned short* gbR1 = gbR + (size_t)128 * I_DIM;
  int wb = wv * 1024;
  int fr = lane & 15, fq = lane >> 4;
  int wm = (wv >> 2) * 64, wn = (wv & 3) * 48;
  f32x4 acc[4][3] = {};
  if (MODE == 2) {
    // loop 1: shared expert (A = hS gathered by token, B = wsd)
    const unsigned short* ga1 = hS + (size_t)tokA * I_DIM + sg * 8;
    const unsigned short* gb1 = wsd + (size_t)n00 * I_DIM + sg * 8;
    const unsigned short* gb11 = gb1 + (size_t)128 * I_DIM;
    DK_KLOOP(ga1, gb1, gb11);
  }
  // main loop (routed for MODE 1/2, shared h for MODE 0)
  DK_KLOOP(gaR, gbR, gbR1);
  // staged epilogue: 4 chunks of 32 rows x 192 cols fp32 (24 KB)
  float* st = (float*)lds;
#pragma unroll
  for (int c = 0; c < 4; c++) {
    __syncthreads();
    if ((wm == 64) == (c >= 2)) {
#pragma unroll
      for (int ii = 0; ii < 2; ii++) {
        int i = (c & 1) * 2 + ii;
#pragma unroll
        for (int j = 0; j < 3; j++)
#pragma unroll
          for (int r = 0; r < 4; r++)
            st[(ii * 16 + fq * 4 + r) * 192 + wn + j * 16 + fr] = acc[i][j][r];
      }
    }
    __syncthreads();
#pragma unroll
    for (int i2 = 0; i2 < 3; i2++) {
      int s = t + i2 * 512;
      int lr = s / 48, qq = s % 48;
      int mloc = mb * 128 + c * 32 + lr;
      int colv = nb * 192 + qq * 4;
      f4 v = *(f4*)&st[lr * 192 + qq * 4];
      if (MODE == 0) {
        *(f4*)&out[(size_t)mloc * H_DIM + colv] = v;
      } else {
        int g = row_lo + mloc;
        int tok = etok[g];
        if (tok >= 0) {
          float* op = &out[(size_t)tok * H_DIM + colv];
          if (MODE == 2) {
            *(f4*)op = v;          // first and only full write of this row
          } else {
            f4 o = *(f4*)op;
            o.x += v.x; o.y += v.y; o.z += v.z; o.w += v.w;
            *(f4*)op = o;
          }
        }
      }
    }
  }
}

// ================= host =======================================================

extern "C" void kernel_launch(void* const* d_in, const int* in_sizes, int n_in,
                              void* d_out, int out_size, void* d_ws, size_t ws_size,
                              hipStream_t stream) {
  const float* x = (const float*)d_in[0];
  const float* sgw = (const float*)d_in[1];
  const float* suw = (const float*)d_in[2];
  const float* sdw = (const float*)d_in[3];
  const float* rgw = (const float*)d_in[4];
  const float* ruw = (const float*)d_in[5];
  const float* rdw = (const float*)d_in[6];
  const float* rw = (const float*)d_in[7];
  const float* rb = (const float*)d_in[8];
  float* out = (float*)d_out;
  char* ws = (char*)d_ws;

  const size_t o_xb = 0;
  const size_t o_w = 37748736;
  const size_t w_sg = o_w;
  const size_t w_su = o_w + 589824;
  const size_t w_sd = o_w + 1179648;
  const size_t w_rg = o_w + 1769472;
  const size_t w_ru = o_w + 6488064;
  const size_t w_rd = o_w + 11206656;
  const size_t o_tki = o_w + 15925248;
  const size_t o_tkw = o_tki + 262144;
  const size_t o_meta = o_tkw + 262144;
  const size_t o_etok = o_meta + 8192;
  const size_t o_ew = o_etok + 270336;
  const size_t o_h = o_ew + 270336;                       // routed h: 67584 rows
  const size_t o_hS = o_h + (size_t)67584 * 1024;         // shared h: 32768 rows
  const size_t need_t2 = o_hS;                            // 123,953,152
  const size_t need_t3 = o_hS + (size_t)32768 * 1024;     // 157,507,584

  unsigned short* xb = (unsigned short*)(ws + o_xb);
  int* tki = (int*)(ws + o_tki);
  float* tkw = (float*)(ws + o_tkw);
  int* counts = (int*)(ws + o_meta);
  int* cursor = counts + 512;
  int* offs16 = counts + 1024;
  int* pcnt16 = counts + 1040;
  int* pinfo = counts + 1056;
  int* etok = (int*)(ws + o_etok);
  float* ew = (float*)(ws + o_ew);
  unsigned short* h = (unsigned short*)(ws + o_h);
  unsigned short* hS = (unsigned short*)(ws + o_hS);

  unsigned short* wsg = (unsigned short*)(ws + w_sg);
  unsigned short* wsu = (unsigned short*)(ws + w_su);
  unsigned short* wsd = (unsigned short*)(ws + w_sd);
  unsigned short* wrg = (unsigned short*)(ws + w_rg);
  unsigned short* wru = (unsigned short*)(ws + w_ru);
  unsigned short* wrd = (unsigned short*)(ws + w_rd);

  hipMemsetAsync(ws + o_meta, 0, 8192, stream);
  hipMemsetAsync(etok, 0xFF, 270336, stream);
  hipMemsetAsync(ew, 0, 270336, stream);   // pads read by gateup (w=0)

  prep_k<<<NB_RT + NB_CW, 256, 0, stream>>>(
      x, xb, rw, rb, tki, tkw, counts,
      sgw, suw, rgw, ruw, sdw, rdw, wsg, wsu, wrg, wru, wsd, wrd);
  scatter_k<<<128, 256, 0, stream>>>(tki, tkw, counts, cursor, etok, ew,
                                     offs16, pcnt16, pinfo);

  if (ws_size >= need_t3) {
    // tier 3: one gateup launch (shared->hS, routed merged->h, w folded);
    // fused shared+primary down (store), then secondary down (RMW).
    gateup_k<<<NB_GU_R + NB_GU_S, 512, 0, stream>>>(
        xb, wsg, wsu, wrg, wru, hS, h, etok, ew, offs16, pcnt16, pinfo,
        NB_GU_R, 0, 1, 66);
    down_k<2><<<792, 512, 0, stream>>>(h, hS, wrd, wsd, out, etok,
                                       offs16, pcnt16, pinfo, 0, 1, 33);
    down_k<1><<<792, 512, 0, stream>>>(h, nullptr, wrd, nullptr, out, etok,
                                       offs16, pcnt16, pinfo, 1, 1, 33);
  } else if (ws_size >= need_t2) {
    // tier 2: single h buffer, merged routed, separate shared down
    gateup_k<<<NB_GU_S, 512, 0, stream>>>(
        xb, wsg, wsu, wrg, wru, h, h, etok, ew, offs16, pcnt16, pinfo,
        0, 0, 1, 66);
    down_k<0><<<768, 512, 0, stream>>>(h, nullptr, wsd, nullptr, out, etok,
                                       offs16, pcnt16, pinfo, 0, 0, 32);
    gateup_k<<<NB_GU_R, 512, 0, stream>>>(
        xb, wsg, wsu, wrg, wru, h, h, etok, ew, offs16, pcnt16, pinfo,
        NB_GU_R, 0, 1, 66);
    down_k<1><<<792, 512, 0, stream>>>(h, nullptr, wrd, nullptr, out, etok,
                                       offs16, pcnt16, pinfo, 0, 1, 33);
    down_k<1><<<792, 512, 0, stream>>>(h, nullptr, wrd, nullptr, out, etok,
                                       offs16, pcnt16, pinfo, 1, 1, 33);
  } else {
    // tier 1: per-phase fallback (h phase-local)
    gateup_k<<<NB_GU_S, 512, 0, stream>>>(
        xb, wsg, wsu, wrg, wru, h, h, etok, ew, offs16, pcnt16, pinfo,
        0, 0, 0, 33);
    down_k<0><<<768, 512, 0, stream>>>(h, nullptr, wsd, nullptr, out, etok,
                                       offs16, pcnt16, pinfo, 0, 0, 32);
    for (int p = 0; p < 2; p++) {
      gateup_k<<<1056, 512, 0, stream>>>(
          xb, wsg, wsu, wrg, wru, h, h, etok, ew, offs16, pcnt16, pinfo,
          1056, p, 0, 33);
      down_k<1><<<792, 512, 0, stream>>>(h, nullptr, wrd, nullptr, out, etok,
                                         offs16, pcnt16, pinfo, p, 0, 33);
    }
  }
}

// Round 15
// 316.839 us; speedup vs baseline: 1.2086x; 1.2086x over previous
//
#include <hip/hip_runtime.h>
#include <stdint.h>

#define T_TOK 32768
#define H_DIM 576
#define I_DIM 512
#define NEXP 8
#define WELEM 294912  // 576*512 elements per expert weight matrix

#define NB_RT 512     // prep: router blocks (64 tokens each)
#define NB_CW 7776    // prep: weight-transpose blocks
#define NB_GU_R 2112  // routed gateup blocks (merged, 528 mb x 4 nb)
#define NB_GU_S 1024  // shared gateup blocks (256 mb x 4 nb)

typedef __attribute__((ext_vector_type(8))) short short8;
typedef __attribute__((ext_vector_type(4))) float f32x4;
typedef __attribute__((ext_vector_type(4))) float f4;
typedef __attribute__((ext_vector_type(4))) unsigned short u16x4;

__device__ __forceinline__ unsigned short f2bf(float f) {
  union { float f; unsigned u; } v; v.f = f;
  unsigned r = (v.u + 0x7fffu + ((v.u >> 16) & 1u)) >> 16;
  return (unsigned short)r;
}

__device__ __forceinline__ void gl16(const void* g, void* l) {
  __builtin_amdgcn_global_load_lds(
      (const __attribute__((address_space(1))) unsigned*)g,
      (__attribute__((address_space(3))) unsigned*)l, 16, 0, 0);
}

// ============ packed prep: router+cvt_x (512 blks) || weight transposes ======
__global__ __launch_bounds__(256) void prep_k(
    const float* __restrict__ x, unsigned short* __restrict__ xb,
    const float* __restrict__ rw, const float* __restrict__ rb,
    int* __restrict__ tki, float* __restrict__ tkw, int* __restrict__ counts,
    const float* __restrict__ sgw, const float* __restrict__ suw,
    const float* __restrict__ rgw, const float* __restrict__ ruw,
    const float* __restrict__ sdw, const float* __restrict__ rdw,
    unsigned short* __restrict__ wsg, unsigned short* __restrict__ wsu,
    unsigned short* __restrict__ wrg, unsigned short* __restrict__ wru,
    unsigned short* __restrict__ wsd, unsigned short* __restrict__ wrd) {
  __shared__ __align__(16) char smem[29312];
  int b = blockIdx.x, tid = threadIdx.x;
  if (b < NB_RT) {
    float* lrw = (float*)smem;                         // 18432 B
    float (*tile)[68] = (float(*)[68])(smem + 18432);  // 8704 B
    float (*red)[8] = (float(*)[8])(smem + 27136);     // 2048 B
    int* hist = (int*)(smem + 29184);                  // 64 B
    for (int i = tid; i < 1152; i += 256)
      *(f4*)&lrw[i * 4] = *(const f4*)&rw[i * 4];
    if (tid < 16) hist[tid] = 0;
    int t0 = b * 64;
    float acc[NEXP] = {};
    for (int c = 0; c < 18; c++) {
      __syncthreads();
#pragma unroll
      for (int k = 0; k < 2; k++) {
        int f = tid + k * 256;
        int rgrp = f >> 8, fl = f & 255;
        int tl2 = fl >> 2, seg = fl & 3;
        int h = rgrp * 288 + c * 16 + seg * 4;
        size_t gi = (size_t)(t0 + tl2) * H_DIM + h;
        f4 v = *(const f4*)(x + gi);
        u16x4 o;
        o.x = f2bf(v.x); o.y = f2bf(v.y); o.z = f2bf(v.z); o.w = f2bf(v.w);
        *(u16x4*)(xb + gi) = o;
        int row = rgrp * 16 + seg * 4;
        tile[row + 0][tl2] = v.x; tile[row + 1][tl2] = v.y;
        tile[row + 2][tl2] = v.z; tile[row + 3][tl2] = v.w;
      }
      __syncthreads();
      if (tid < 128) {
        int half = tid >> 6, tl = tid & 63;
        int hbase = half * 288 + c * 16;
        int rbase = half * 16;
#pragma unroll
        for (int hh = 0; hh < 16; hh++) {
          float xv = tile[rbase + hh][tl];
          f4 w0 = *(const f4*)&lrw[(hbase + hh) * 8];
          f4 w1 = *(const f4*)&lrw[(hbase + hh) * 8 + 4];
          acc[0] += xv * w0.x; acc[1] += xv * w0.y;
          acc[2] += xv * w0.z; acc[3] += xv * w0.w;
          acc[4] += xv * w1.x; acc[5] += xv * w1.y;
          acc[6] += xv * w1.z; acc[7] += xv * w1.w;
        }
      }
    }
    if (tid >= 64 && tid < 128) {
      int tl = tid & 63;
#pragma unroll
      for (int e = 0; e < NEXP; e++) red[tl][e] = acc[e];
    }
    __syncthreads();
    if (tid < 64) {
      int t = t0 + tid;
      float l[NEXP];
#pragma unroll
      for (int e = 0; e < NEXP; e++) l[e] = acc[e] + red[tid][e] + rb[e];
      int e0 = 0;
#pragma unroll
      for (int e = 1; e < NEXP; e++) if (l[e] > l[e0]) e0 = e;
      int e1 = -1;
#pragma unroll
      for (int e = 0; e < NEXP; e++) {
        if (e == e0) continue;
        if (e1 < 0 || l[e] > l[e1]) e1 = e;
      }
      float w0 = 1.f / (1.f + __expf(l[e1] - l[e0]));
      tki[t * 2] = e0; tki[t * 2 + 1] = e1;
      tkw[t * 2] = w0; tkw[t * 2 + 1] = 1.f - w0;
      atomicAdd(&hist[e0], 1);
      atomicAdd(&hist[8 + e1], 1);
    }
    __syncthreads();
    if (tid < 16) atomicAdd(&counts[tid * 32], hist[tid]);
  } else {
    float (*tile)[33] = (float(*)[33])smem;
    int b0 = b - NB_RT;
    const float* src; unsigned short* dst;
    int C, bx, by;
    if (b0 < 5184) {
      int z = b0 / 288, r = b0 % 288;
      bx = r & 15; by = r >> 4; C = 512;
      if (z == 0)      { src = sgw;                            dst = wsg; }
      else if (z == 1) { src = suw;                            dst = wsu; }
      else if (z < 10) { src = rgw + (size_t)(z - 2) * WELEM;  dst = wrg + (size_t)(z - 2) * WELEM; }
      else             { src = ruw + (size_t)(z - 10) * WELEM; dst = wru + (size_t)(z - 10) * WELEM; }
    } else {
      int b2 = b0 - 5184;
      int z = b2 / 288, r = b2 % 288;
      bx = r % 18; by = r / 18; C = 576;
      src = (z == 0) ? sdw : rdw + (size_t)(z - 1) * WELEM;
      dst = (z == 0) ? wsd : wrd + (size_t)(z - 1) * WELEM;
    }
    int R = 1088 - C;
    int tx = tid & 31, ty = tid >> 5;
    int r0 = by * 32, c0 = bx * 32;
    for (int i = ty; i < 32; i += 8)
      tile[i][tx] = src[(size_t)(r0 + i) * C + c0 + tx];
    __syncthreads();
    for (int i = ty; i < 32; i += 8)
      dst[(size_t)(c0 + i) * R + r0 + tx] = f2bf(tile[tx][i]);
  }
}

// ============ scatter with fused offsets scan ================================
__global__ __launch_bounds__(256) void scatter_k(
    const int* __restrict__ tki, const float* __restrict__ tkw,
    const int* __restrict__ counts, int* __restrict__ cursor /*stride 32*/,
    int* __restrict__ etok, float* __restrict__ ew,
    int* __restrict__ offs16g, int* __restrict__ pcnt16g,
    int* __restrict__ pinfog) {
  __shared__ int soffs[16], hist[16], base[16], lcur[16];
  int tid = threadIdx.x;
  if (tid == 0) {
    int o = 0, p0 = 0;
    for (int s = 0; s < 16; s++) {
      int c = counts[s * 32];
      int pc = (c + 127) & ~127;
      soffs[s] = o;
      if (blockIdx.x == 0) { offs16g[s] = o; pcnt16g[s] = pc; }
      o += pc;
      if (s == 7) p0 = o;
    }
    if (blockIdx.x == 0) { pinfog[0] = p0; pinfog[1] = o - p0; }
  }
  if (tid < 16) { hist[tid] = 0; lcur[tid] = 0; }
  __syncthreads();
  int t = blockIdx.x * 256 + tid;
  int s0 = tki[t * 2], s1 = 8 + tki[t * 2 + 1];
  atomicAdd(&hist[s0], 1);
  atomicAdd(&hist[s1], 1);
  __syncthreads();
  if (tid < 16) base[tid] = atomicAdd(&cursor[tid * 32], hist[tid]);
  __syncthreads();
#pragma unroll
  for (int k = 0; k < 2; k++) {
    int s = (k == 0) ? s0 : s1;
    int r = atomicAdd(&lcur[s], 1);
    int slot = soffs[s] + base[s] + r;
    etok[slot] = t;
    ew[slot] = tkw[t * 2 + k];
  }
}

// ---------------- fused gate/up GEMM + silu, runtime routed/shared -----------
// Routing weight fold: h = bf16(w * silu(g) * u). ew is staged into LDS via
// ONE global_load_lds before the K-loop (latency hidden by the GEMM); the
// epilogue reads it as a broadcast LDS load. ZERO loop-live VGPR cost --
// r14 lesson: 16 hoisted VGPRs crossed the 64-VGPR cliff (occ 39->22%, +59us).
__global__ __launch_bounds__(512, 2) void gateup_k(
    const unsigned short* __restrict__ xb,
    const unsigned short* __restrict__ wg_s, const unsigned short* __restrict__ wu_s,
    const unsigned short* __restrict__ wg_r, const unsigned short* __restrict__ wu_r,
    unsigned short* __restrict__ h_s, unsigned short* __restrict__ h_r,
    const int* __restrict__ etok, const float* __restrict__ ew,
    const int* __restrict__ offs16, const int* __restrict__ pcnt16,
    const int* __restrict__ pinfo,
    int nrg, int p, int merged, int mchunk_r) {
  int bid = blockIdx.x;
  bool routed = bid < nrg;
  int mb, nb;
  if (routed) {
    int xcd = bid & 7, l = bid >> 3;
    mb = xcd * mchunk_r + (l >> 2);
    nb = l & 3;
    int nrows = merged ? pinfo[0] + pinfo[1] : pinfo[p];
    if (mb * 128 >= nrows) return;
  } else {
    int b2 = bid - nrg;
    int xcd = b2 & 7, l = b2 >> 3;
    mb = xcd * 32 + (l >> 2);
    nb = l & 3;
  }
  __shared__ unsigned short As[128 * 32];
  __shared__ unsigned short Bg[128 * 32];
  __shared__ unsigned short Bu[128 * 32];
  __shared__ float ewLds[128];   // 512 B
  int t = threadIdx.x;
  int wv = t >> 6, lane = t & 63;
  int ar = t >> 2, seg = t & 3;
  int sg = seg ^ ((ar >> 1) & 3);
  int m0 = mb * 128 + ar;
  int tok0;
  const unsigned short *wgp, *wup;
  unsigned short* hp;
  const float* ewp = nullptr;
  if (routed) {
    int rl = (!merged && p) ? pinfo[0] : 0;
    int g = rl + m0;
    int s = 0;
#pragma unroll
    for (int i = 0; i < 15; i++) s += (g >= offs16[i] + pcnt16[i]) ? 1 : 0;
    int e = s & 7;
    tok0 = etok[g];
    if (tok0 < 0) tok0 = 0;
    wgp = wg_r + (size_t)e * WELEM;
    wup = wu_r + (size_t)e * WELEM;
    hp = h_r;
    ewp = ew + rl;
  } else {
    tok0 = m0;
    wgp = wg_s;
    wup = wu_s;
    hp = h_s;
  }
  // async-stage the block's 128 routing weights into LDS (wave 0, 32 lanes);
  // completes at the first __syncthreads (vmcnt drain), read only in epilogue.
  if (routed && t < 32) gl16(ewp + mb * 128 + t * 4, ewLds);
  const unsigned short* ga = xb + (size_t)tok0 * H_DIM + sg * 8;
  int n0 = nb * 128 + ar;
  const unsigned short* gg = wgp + (size_t)n0 * H_DIM + sg * 8;
  const unsigned short* gu = wup + (size_t)n0 * H_DIM + sg * 8;
  char* lA = (char*)As + wv * 1024;
  char* lG = (char*)Bg + wv * 1024;
  char* lU = (char*)Bu + wv * 1024;
  int fr = lane & 15, fq = lane >> 4;
  int wm = (wv >> 2) * 64, wn = (wv & 3) * 32;
  f32x4 accg[4][2] = {};
  f32x4 accu[4][2] = {};
  for (int k0 = 0; k0 < H_DIM; k0 += 32) {
    gl16(ga + k0, lA);
    gl16(gg + k0, lG);
    gl16(gu + k0, lU);
    __syncthreads();
    short8 a[4], g[2], u[2];
#pragma unroll
    for (int i = 0; i < 4; i++) {
      int r = wm + i * 16 + fr;
      a[i] = *(const short8*)&As[r * 32 + (fq ^ ((r >> 1) & 3)) * 8];
    }
#pragma unroll
    for (int j = 0; j < 2; j++) {
      int r = wn + j * 16 + fr;
      int sw = (fq ^ ((r >> 1) & 3)) * 8;
      g[j] = *(const short8*)&Bg[r * 32 + sw];
      u[j] = *(const short8*)&Bu[r * 32 + sw];
    }
#pragma unroll
    for (int i = 0; i < 4; i++)
#pragma unroll
      for (int j = 0; j < 2; j++) {
        accg[i][j] = __builtin_amdgcn_mfma_f32_16x16x32_bf16(a[i], g[j], accg[i][j], 0, 0, 0);
        accu[i][j] = __builtin_amdgcn_mfma_f32_16x16x32_bf16(a[i], u[j], accu[i][j], 0, 0, 0);
      }
    __syncthreads();
  }
#pragma unroll
  for (int i = 0; i < 4; i++)
#pragma unroll
    for (int j = 0; j < 2; j++)
#pragma unroll
      for (int r = 0; r < 4; r++) {
        int row = mb * 128 + wm + i * 16 + fq * 4 + r;
        int col = nb * 128 + wn + j * 16 + fr;
        float gv = accg[i][j][r], uv = accu[i][j][r];
        float hv = (gv / (1.f + __expf(-gv))) * uv;
        if (routed) hv *= ewLds[wm + i * 16 + fq * 4 + r];  // LDS broadcast
        hp[(size_t)row * I_DIM + col] = f2bf(hv);
      }
}

// ---------------- down GEMM: 128x192 tile ------------------------------------
// MODE 0: shared store. MODE 1: routed RMW out += v (h pre-scaled by w).
// MODE 2: fused shared+primary -- TWO K-loops into one accumulator:
//         acc = hS[tok]*wsd + h[slot]*wrd[e]; single STORE of out[tok].
#define DK_KLOOP(GA, GB0, GB1)                                              \
  for (int k0 = 0; k0 < I_DIM; k0 += 32) {                                  \
    gl16((GA) + k0, (char*)Ab + wb);                                        \
    gl16((GB0) + k0, (char*)Bb + wb);                                       \
    if (t < 256) gl16((GB1) + k0, (char*)Bb + 8192 + wb);                   \
    __syncthreads();                                                        \
    short8 a[4], b2[3];                                                     \
    _Pragma("unroll") for (int i = 0; i < 4; i++) {                         \
      int r = wm + i * 16 + fr;                                             \
      a[i] = *(const short8*)&Ab[r * 32 + (fq ^ ((r >> 1) & 3)) * 8];       \
    }                                                                       \
    _Pragma("unroll") for (int j = 0; j < 3; j++) {                         \
      int r = wn + j * 16 + fr;                                             \
      b2[j] = *(const short8*)&Bb[r * 32 + (fq ^ ((r >> 1) & 3)) * 8];      \
    }                                                                       \
    _Pragma("unroll") for (int i = 0; i < 4; i++)                           \
      _Pragma("unroll") for (int j = 0; j < 3; j++)                         \
        acc[i][j] = __builtin_amdgcn_mfma_f32_16x16x32_bf16(a[i], b2[j],    \
                                                            acc[i][j], 0, 0, 0); \
    __syncthreads();                                                        \
  }

template <int MODE>
__global__ __launch_bounds__(512, 2) void down_k(
    const unsigned short* __restrict__ hbuf, const unsigned short* __restrict__ hS,
    const unsigned short* __restrict__ wd, const unsigned short* __restrict__ wsd,
    float* __restrict__ out, const int* __restrict__ etok,
    const int* __restrict__ offs16, const int* __restrict__ pcnt16,
    const int* __restrict__ pinfo, int p, int merged, int mchunk) {
  int bid = blockIdx.x;
  int xcd = bid & 7, l = bid >> 3;
  int mb = xcd * mchunk + l / 3;
  int nb = l % 3;
  int nrows = (MODE == 0) ? T_TOK : pinfo[p];
  if (mb * 128 >= nrows) return;
  int row_lo = (MODE == 1 && p == 1) ? pinfo[0] : 0;
  int hrow_lo = (MODE == 1 && merged) ? row_lo : 0;
  __shared__ char lds[24576];  // A 8KB | B 12KB ; epilogue fp32 32x192
  unsigned short* Ab = (unsigned short*)lds;
  unsigned short* Bb = (unsigned short*)(lds + 8192);
  int t = threadIdx.x;
  int wv = t >> 6, lane = t & 63;
  int ar = t >> 2, seg = t & 3;
  int sg = seg ^ ((ar >> 1) & 3);
  int e = 0, tokA = 0;
  if (MODE >= 1) {
    int g = row_lo + mb * 128 + ar;
    int s = 0;
#pragma unroll
    for (int i = 0; i < 15; i++) s += (g >= offs16[i] + pcnt16[i]) ? 1 : 0;
    e = s & 7;
    if (MODE == 2) {
      int tk = etok[g];
      tokA = (tk < 0) ? 0 : tk;
    }
  }
  const unsigned short* gaR = hbuf + (size_t)(hrow_lo + mb * 128 + ar) * I_DIM + sg * 8;
  int n00 = nb * 192 + ar;
  const unsigned short* gbR = wd + (size_t)e * WELEM + (size_t)n00 * I_DIM + sg * 8;
  const unsigned short* gbR1 = gbR + (size_t)128 * I_DIM;
  int wb = wv * 1024;
  int fr = lane & 15, fq = lane >> 4;
  int wm = (wv >> 2) * 64, wn = (wv & 3) * 48;
  f32x4 acc[4][3] = {};
  if (MODE == 2) {
    // loop 1: shared expert (A = hS gathered by token, B = wsd)
    const unsigned short* ga1 = hS + (size_t)tokA * I_DIM + sg * 8;
    const unsigned short* gb1 = wsd + (size_t)n00 * I_DIM + sg * 8;
    const unsigned short* gb11 = gb1 + (size_t)128 * I_DIM;
    DK_KLOOP(ga1, gb1, gb11);
  }
  // main loop (routed for MODE 1/2, shared h for MODE 0)
  DK_KLOOP(gaR, gbR, gbR1);
  // staged epilogue: 4 chunks of 32 rows x 192 cols fp32 (24 KB)
  float* st = (float*)lds;
#pragma unroll
  for (int c = 0; c < 4; c++) {
    __syncthreads();
    if ((wm == 64) == (c >= 2)) {
#pragma unroll
      for (int ii = 0; ii < 2; ii++) {
        int i = (c & 1) * 2 + ii;
#pragma unroll
        for (int j = 0; j < 3; j++)
#pragma unroll
          for (int r = 0; r < 4; r++)
            st[(ii * 16 + fq * 4 + r) * 192 + wn + j * 16 + fr] = acc[i][j][r];
      }
    }
    __syncthreads();
#pragma unroll
    for (int i2 = 0; i2 < 3; i2++) {
      int s = t + i2 * 512;
      int lr = s / 48, qq = s % 48;
      int mloc = mb * 128 + c * 32 + lr;
      int colv = nb * 192 + qq * 4;
      f4 v = *(f4*)&st[lr * 192 + qq * 4];
      if (MODE == 0) {
        *(f4*)&out[(size_t)mloc * H_DIM + colv] = v;
      } else {
        int g = row_lo + mloc;
        int tok = etok[g];
        if (tok >= 0) {
          float* op = &out[(size_t)tok * H_DIM + colv];
          if (MODE == 2) {
            *(f4*)op = v;          // first and only full write of this row
          } else {
            f4 o = *(f4*)op;
            o.x += v.x; o.y += v.y; o.z += v.z; o.w += v.w;
            *(f4*)op = o;
          }
        }
      }
    }
  }
}

// ================= host =======================================================

extern "C" void kernel_launch(void* const* d_in, const int* in_sizes, int n_in,
                              void* d_out, int out_size, void* d_ws, size_t ws_size,
                              hipStream_t stream) {
  const float* x = (const float*)d_in[0];
  const float* sgw = (const float*)d_in[1];
  const float* suw = (const float*)d_in[2];
  const float* sdw = (const float*)d_in[3];
  const float* rgw = (const float*)d_in[4];
  const float* ruw = (const float*)d_in[5];
  const float* rdw = (const float*)d_in[6];
  const float* rw = (const float*)d_in[7];
  const float* rb = (const float*)d_in[8];
  float* out = (float*)d_out;
  char* ws = (char*)d_ws;

  const size_t o_xb = 0;
  const size_t o_w = 37748736;
  const size_t w_sg = o_w;
  const size_t w_su = o_w + 589824;
  const size_t w_sd = o_w + 1179648;
  const size_t w_rg = o_w + 1769472;
  const size_t w_ru = o_w + 6488064;
  const size_t w_rd = o_w + 11206656;
  const size_t o_tki = o_w + 15925248;
  const size_t o_tkw = o_tki + 262144;
  const size_t o_meta = o_tkw + 262144;
  const size_t o_etok = o_meta + 8192;
  const size_t o_ew = o_etok + 270336;
  const size_t o_h = o_ew + 270336;                       // routed h: 67584 rows
  const size_t o_hS = o_h + (size_t)67584 * 1024;         // shared h: 32768 rows
  const size_t need_t2 = o_hS;                            // 123,953,152
  const size_t need_t3 = o_hS + (size_t)32768 * 1024;     // 157,507,584

  unsigned short* xb = (unsigned short*)(ws + o_xb);
  int* tki = (int*)(ws + o_tki);
  float* tkw = (float*)(ws + o_tkw);
  int* counts = (int*)(ws + o_meta);
  int* cursor = counts + 512;
  int* offs16 = counts + 1024;
  int* pcnt16 = counts + 1040;
  int* pinfo = counts + 1056;
  int* etok = (int*)(ws + o_etok);
  float* ew = (float*)(ws + o_ew);
  unsigned short* h = (unsigned short*)(ws + o_h);
  unsigned short* hS = (unsigned short*)(ws + o_hS);

  unsigned short* wsg = (unsigned short*)(ws + w_sg);
  unsigned short* wsu = (unsigned short*)(ws + w_su);
  unsigned short* wsd = (unsigned short*)(ws + w_sd);
  unsigned short* wrg = (unsigned short*)(ws + w_rg);
  unsigned short* wru = (unsigned short*)(ws + w_ru);
  unsigned short* wrd = (unsigned short*)(ws + w_rd);

  hipMemsetAsync(ws + o_meta, 0, 8192, stream);
  hipMemsetAsync(etok, 0xFF, 270336, stream);
  hipMemsetAsync(ew, 0, 270336, stream);   // pads read by gateup (w=0)

  prep_k<<<NB_RT + NB_CW, 256, 0, stream>>>(
      x, xb, rw, rb, tki, tkw, counts,
      sgw, suw, rgw, ruw, sdw, rdw, wsg, wsu, wrg, wru, wsd, wrd);
  scatter_k<<<128, 256, 0, stream>>>(tki, tkw, counts, cursor, etok, ew,
                                     offs16, pcnt16, pinfo);

  if (ws_size >= need_t3) {
    // tier 3: one gateup launch (shared->hS, routed merged->h, w folded);
    // fused shared+primary down (store), then secondary down (RMW).
    gateup_k<<<NB_GU_R + NB_GU_S, 512, 0, stream>>>(
        xb, wsg, wsu, wrg, wru, hS, h, etok, ew, offs16, pcnt16, pinfo,
        NB_GU_R, 0, 1, 66);
    down_k<2><<<792, 512, 0, stream>>>(h, hS, wrd, wsd, out, etok,
                                       offs16, pcnt16, pinfo, 0, 1, 33);
    down_k<1><<<792, 512, 0, stream>>>(h, nullptr, wrd, nullptr, out, etok,
                                       offs16, pcnt16, pinfo, 1, 1, 33);
  } else if (ws_size >= need_t2) {
    // tier 2: single h buffer, merged routed, separate shared down
    gateup_k<<<NB_GU_S, 512, 0, stream>>>(
        xb, wsg, wsu, wrg, wru, h, h, etok, ew, offs16, pcnt16, pinfo,
        0, 0, 1, 66);
    down_k<0><<<768, 512, 0, stream>>>(h, nullptr, wsd, nullptr, out, etok,
                                       offs16, pcnt16, pinfo, 0, 0, 32);
    gateup_k<<<NB_GU_R, 512, 0, stream>>>(
        xb, wsg, wsu, wrg, wru, h, h, etok, ew, offs16, pcnt16, pinfo,
        NB_GU_R, 0, 1, 66);
    down_k<1><<<792, 512, 0, stream>>>(h, nullptr, wrd, nullptr, out, etok,
                                       offs16, pcnt16, pinfo, 0, 1, 33);
    down_k<1><<<792, 512, 0, stream>>>(h, nullptr, wrd, nullptr, out, etok,
                                       offs16, pcnt16, pinfo, 1, 1, 33);
  } else {
    // tier 1: per-phase fallback (h phase-local)
    gateup_k<<<NB_GU_S, 512, 0, stream>>>(
        xb, wsg, wsu, wrg, wru, h, h, etok, ew, offs16, pcnt16, pinfo,
        0, 0, 0, 33);
    down_k<0><<<768, 512, 0, stream>>>(h, nullptr, wsd, nullptr, out, etok,
                                       offs16, pcnt16, pinfo, 0, 0, 32);
    for (int p = 0; p < 2; p++) {
      gateup_k<<<1056, 512, 0, stream>>>(
          xb, wsg, wsu, wrg, wru, h, h, etok, ew, offs16, pcnt16, pinfo,
          1056, p, 0, 33);
      down_k<1><<<792, 512, 0, stream>>>(h, nullptr, wrd, nullptr, out, etok,
                                         offs16, pcnt16, pinfo, p, 0, 33);
    }
  }
}

// Round 16
// 287.519 us; speedup vs baseline: 1.3319x; 1.1020x over previous
//
#include <hip/hip_runtime.h>
#include <stdint.h>

#define T_TOK 32768
#define H_DIM 576
#define I_DIM 512
#define NEXP 8
#define WELEM 294912  // 576*512 elements per expert weight matrix

#define NB_RT 512     // prep: router blocks (64 tokens each)
#define NB_CW 7776    // prep: weight-transpose blocks
#define NB_GU_R 2112  // routed gateup blocks (merged, 528 mb x 4 nb)
#define NB_GU_S 1024  // shared gateup blocks (256 mb x 4 nb)

typedef __attribute__((ext_vector_type(8))) short short8;
typedef __attribute__((ext_vector_type(4))) float f32x4;
typedef __attribute__((ext_vector_type(4))) float f4;
typedef __attribute__((ext_vector_type(4))) unsigned short u16x4;

__device__ __forceinline__ unsigned short f2bf(float f) {
  union { float f; unsigned u; } v; v.f = f;
  unsigned r = (v.u + 0x7fffu + ((v.u >> 16) & 1u)) >> 16;
  return (unsigned short)r;
}

__device__ __forceinline__ void gl16(const void* g, void* l) {
  __builtin_amdgcn_global_load_lds(
      (const __attribute__((address_space(1))) unsigned*)g,
      (__attribute__((address_space(3))) unsigned*)l, 16, 0, 0);
}

// ============ packed prep: router+cvt_x (512 blks) || weight transposes ======
__global__ __launch_bounds__(256) void prep_k(
    const float* __restrict__ x, unsigned short* __restrict__ xb,
    const float* __restrict__ rw, const float* __restrict__ rb,
    int* __restrict__ tki, float* __restrict__ tkw, int* __restrict__ counts,
    const float* __restrict__ sgw, const float* __restrict__ suw,
    const float* __restrict__ rgw, const float* __restrict__ ruw,
    const float* __restrict__ sdw, const float* __restrict__ rdw,
    unsigned short* __restrict__ wsg, unsigned short* __restrict__ wsu,
    unsigned short* __restrict__ wrg, unsigned short* __restrict__ wru,
    unsigned short* __restrict__ wsd, unsigned short* __restrict__ wrd) {
  __shared__ __align__(16) char smem[29312];
  int b = blockIdx.x, tid = threadIdx.x;
  if (b < NB_RT) {
    float* lrw = (float*)smem;                         // 18432 B
    float (*tile)[68] = (float(*)[68])(smem + 18432);  // 8704 B
    float (*red)[8] = (float(*)[8])(smem + 27136);     // 2048 B
    int* hist = (int*)(smem + 29184);                  // 64 B
    for (int i = tid; i < 1152; i += 256)
      *(f4*)&lrw[i * 4] = *(const f4*)&rw[i * 4];
    if (tid < 16) hist[tid] = 0;
    int t0 = b * 64;
    float acc[NEXP] = {};
    for (int c = 0; c < 18; c++) {
      __syncthreads();
#pragma unroll
      for (int k = 0; k < 2; k++) {
        int f = tid + k * 256;
        int rgrp = f >> 8, fl = f & 255;
        int tl2 = fl >> 2, seg = fl & 3;
        int h = rgrp * 288 + c * 16 + seg * 4;
        size_t gi = (size_t)(t0 + tl2) * H_DIM + h;
        f4 v = *(const f4*)(x + gi);
        u16x4 o;
        o.x = f2bf(v.x); o.y = f2bf(v.y); o.z = f2bf(v.z); o.w = f2bf(v.w);
        *(u16x4*)(xb + gi) = o;
        int row = rgrp * 16 + seg * 4;
        tile[row + 0][tl2] = v.x; tile[row + 1][tl2] = v.y;
        tile[row + 2][tl2] = v.z; tile[row + 3][tl2] = v.w;
      }
      __syncthreads();
      if (tid < 128) {
        int half = tid >> 6, tl = tid & 63;
        int hbase = half * 288 + c * 16;
        int rbase = half * 16;
#pragma unroll
        for (int hh = 0; hh < 16; hh++) {
          float xv = tile[rbase + hh][tl];
          f4 w0 = *(const f4*)&lrw[(hbase + hh) * 8];
          f4 w1 = *(const f4*)&lrw[(hbase + hh) * 8 + 4];
          acc[0] += xv * w0.x; acc[1] += xv * w0.y;
          acc[2] += xv * w0.z; acc[3] += xv * w0.w;
          acc[4] += xv * w1.x; acc[5] += xv * w1.y;
          acc[6] += xv * w1.z; acc[7] += xv * w1.w;
        }
      }
    }
    if (tid >= 64 && tid < 128) {
      int tl = tid & 63;
#pragma unroll
      for (int e = 0; e < NEXP; e++) red[tl][e] = acc[e];
    }
    __syncthreads();
    if (tid < 64) {
      int t = t0 + tid;
      float l[NEXP];
#pragma unroll
      for (int e = 0; e < NEXP; e++) l[e] = acc[e] + red[tid][e] + rb[e];
      int e0 = 0;
#pragma unroll
      for (int e = 1; e < NEXP; e++) if (l[e] > l[e0]) e0 = e;
      int e1 = -1;
#pragma unroll
      for (int e = 0; e < NEXP; e++) {
        if (e == e0) continue;
        if (e1 < 0 || l[e] > l[e1]) e1 = e;
      }
      float w0 = 1.f / (1.f + __expf(l[e1] - l[e0]));
      tki[t * 2] = e0; tki[t * 2 + 1] = e1;
      tkw[t * 2] = w0; tkw[t * 2 + 1] = 1.f - w0;
      atomicAdd(&hist[e0], 1);
      atomicAdd(&hist[8 + e1], 1);
    }
    __syncthreads();
    if (tid < 16) atomicAdd(&counts[tid * 32], hist[tid]);
  } else {
    float (*tile)[33] = (float(*)[33])smem;
    int b0 = b - NB_RT;
    const float* src; unsigned short* dst;
    int C, bx, by;
    if (b0 < 5184) {
      int z = b0 / 288, r = b0 % 288;
      bx = r & 15; by = r >> 4; C = 512;
      if (z == 0)      { src = sgw;                            dst = wsg; }
      else if (z == 1) { src = suw;                            dst = wsu; }
      else if (z < 10) { src = rgw + (size_t)(z - 2) * WELEM;  dst = wrg + (size_t)(z - 2) * WELEM; }
      else             { src = ruw + (size_t)(z - 10) * WELEM; dst = wru + (size_t)(z - 10) * WELEM; }
    } else {
      int b2 = b0 - 5184;
      int z = b2 / 288, r = b2 % 288;
      bx = r % 18; by = r / 18; C = 576;
      src = (z == 0) ? sdw : rdw + (size_t)(z - 1) * WELEM;
      dst = (z == 0) ? wsd : wrd + (size_t)(z - 1) * WELEM;
    }
    int R = 1088 - C;
    int tx = tid & 31, ty = tid >> 5;
    int r0 = by * 32, c0 = bx * 32;
    for (int i = ty; i < 32; i += 8)
      tile[i][tx] = src[(size_t)(r0 + i) * C + c0 + tx];
    __syncthreads();
    for (int i = ty; i < 32; i += 8)
      dst[(size_t)(c0 + i) * R + r0 + tx] = f2bf(tile[tx][i]);
  }
}

// ============ scatter with fused offsets scan ================================
__global__ __launch_bounds__(256) void scatter_k(
    const int* __restrict__ tki, const float* __restrict__ tkw,
    const int* __restrict__ counts, int* __restrict__ cursor /*stride 32*/,
    int* __restrict__ etok, float* __restrict__ ew,
    int* __restrict__ offs16g, int* __restrict__ pcnt16g,
    int* __restrict__ pinfog) {
  __shared__ int soffs[16], hist[16], base[16], lcur[16];
  int tid = threadIdx.x;
  if (tid == 0) {
    int o = 0, p0 = 0;
    for (int s = 0; s < 16; s++) {
      int c = counts[s * 32];
      int pc = (c + 127) & ~127;
      soffs[s] = o;
      if (blockIdx.x == 0) { offs16g[s] = o; pcnt16g[s] = pc; }
      o += pc;
      if (s == 7) p0 = o;
    }
    if (blockIdx.x == 0) { pinfog[0] = p0; pinfog[1] = o - p0; }
  }
  if (tid < 16) { hist[tid] = 0; lcur[tid] = 0; }
  __syncthreads();
  int t = blockIdx.x * 256 + tid;
  int s0 = tki[t * 2], s1 = 8 + tki[t * 2 + 1];
  atomicAdd(&hist[s0], 1);
  atomicAdd(&hist[s1], 1);
  __syncthreads();
  if (tid < 16) base[tid] = atomicAdd(&cursor[tid * 32], hist[tid]);
  __syncthreads();
#pragma unroll
  for (int k = 0; k < 2; k++) {
    int s = (k == 0) ? s0 : s1;
    int r = atomicAdd(&lcur[s], 1);
    int slot = soffs[s] + base[s] + r;
    etok[slot] = t;
    ew[slot] = tkw[t * 2 + k];
  }
}

// ---------------- fused gate/up GEMM + silu, BK=64 ---------------------------
// BK 32->64: barriers/drains halve (36->18). LDS 48.6KB; occupancy reg-capped
// at 2 blocks/CU either way (r9/r16 analysis). Swizzle: 128B rows, slot
// (s*4+fq)^(row&7) => 2-way bank alias (free). Pre-swizzled staging col
// sigma=(t&7)^((t>>3)&7), pass-invariant (64&7=0). MFMA k-order unchanged.
__global__ __launch_bounds__(512, 2) void gateup_k(
    const unsigned short* __restrict__ xb,
    const unsigned short* __restrict__ wg_s, const unsigned short* __restrict__ wu_s,
    const unsigned short* __restrict__ wg_r, const unsigned short* __restrict__ wu_r,
    unsigned short* __restrict__ h_s, unsigned short* __restrict__ h_r,
    const int* __restrict__ etok, const float* __restrict__ ew,
    const int* __restrict__ offs16, const int* __restrict__ pcnt16,
    const int* __restrict__ pinfo,
    int nrg, int p, int merged, int mchunk_r) {
  int bid = blockIdx.x;
  bool routed = bid < nrg;
  int mb, nb;
  if (routed) {
    int xcd = bid & 7, l = bid >> 3;
    mb = xcd * mchunk_r + (l >> 2);
    nb = l & 3;
    int nrows = merged ? pinfo[0] + pinfo[1] : pinfo[p];
    if (mb * 128 >= nrows) return;
  } else {
    int b2 = bid - nrg;
    int xcd = b2 & 7, l = b2 >> 3;
    mb = xcd * 32 + (l >> 2);
    nb = l & 3;
  }
  __shared__ unsigned short As[128 * 64];
  __shared__ unsigned short Bg[128 * 64];
  __shared__ unsigned short Bu[128 * 64];
  __shared__ float ewLds[128];
  int t = threadIdx.x;
  int wv = t >> 6, lane = t & 63;
  int q = t >> 3;                    // staging row (pass 0), 0..63
  int sg8 = (t & 7) ^ (q & 7);       // pre-swizzled 16B slot
  int tok0, tok1;
  const unsigned short *wgp, *wup;
  unsigned short* hp;
  const float* ewp = nullptr;
  if (routed) {
    int rl = (!merged && p) ? pinfo[0] : 0;
    int g = rl + mb * 128 + q;
    int s = 0;
#pragma unroll
    for (int i = 0; i < 15; i++) s += (g >= offs16[i] + pcnt16[i]) ? 1 : 0;
    int e = s & 7;
    tok0 = etok[g];
    if (tok0 < 0) tok0 = 0;
    tok1 = etok[g + 64];
    if (tok1 < 0) tok1 = 0;
    wgp = wg_r + (size_t)e * WELEM;
    wup = wu_r + (size_t)e * WELEM;
    hp = h_r;
    ewp = ew + rl;
  } else {
    tok0 = mb * 128 + q;
    tok1 = tok0 + 64;
    wgp = wg_s;
    wup = wu_s;
    hp = h_s;
  }
  if (routed && t < 32) gl16(ewp + mb * 128 + t * 4, ewLds);
  const unsigned short* ga0 = xb + (size_t)tok0 * H_DIM + sg8 * 8;
  const unsigned short* ga1 = xb + (size_t)tok1 * H_DIM + sg8 * 8;
  int n0 = nb * 128 + q;
  const unsigned short* gg = wgp + (size_t)n0 * H_DIM + sg8 * 8;
  const unsigned short* gu = wup + (size_t)n0 * H_DIM + sg8 * 8;
  int wb = wv * 1024;
  int fr = lane & 15, fq = lane >> 4;
  int wm = (wv >> 2) * 64, wn = (wv & 3) * 32;
  f32x4 accg[4][2] = {};
  f32x4 accu[4][2] = {};
  for (int k0 = 0; k0 < H_DIM; k0 += 64) {
    gl16(ga0 + k0, (char*)As + wb);
    gl16(ga1 + k0, (char*)As + 8192 + wb);
    gl16(gg + k0, (char*)Bg + wb);
    gl16(gg + 36864 + k0, (char*)Bg + 8192 + wb);   // +64 rows * 576
    gl16(gu + k0, (char*)Bu + wb);
    gl16(gu + 36864 + k0, (char*)Bu + 8192 + wb);
    __syncthreads();
#pragma unroll
    for (int s = 0; s < 2; s++) {
      short8 a[4], g2[2], u2[2];
#pragma unroll
      for (int i = 0; i < 4; i++) {
        int r = wm + i * 16 + fr;
        a[i] = *(const short8*)&As[r * 64 + (((s << 2) + fq) ^ (r & 7)) * 8];
      }
#pragma unroll
      for (int j = 0; j < 2; j++) {
        int r = wn + j * 16 + fr;
        int sw = (((s << 2) + fq) ^ (r & 7)) * 8;
        g2[j] = *(const short8*)&Bg[r * 64 + sw];
        u2[j] = *(const short8*)&Bu[r * 64 + sw];
      }
#pragma unroll
      for (int i = 0; i < 4; i++)
#pragma unroll
        for (int j = 0; j < 2; j++) {
          accg[i][j] = __builtin_amdgcn_mfma_f32_16x16x32_bf16(a[i], g2[j], accg[i][j], 0, 0, 0);
          accu[i][j] = __builtin_amdgcn_mfma_f32_16x16x32_bf16(a[i], u2[j], accu[i][j], 0, 0, 0);
        }
    }
    __syncthreads();
  }
#pragma unroll
  for (int i = 0; i < 4; i++)
#pragma unroll
    for (int j = 0; j < 2; j++)
#pragma unroll
      for (int r = 0; r < 4; r++) {
        int row = mb * 128 + wm + i * 16 + fq * 4 + r;
        int col = nb * 128 + wn + j * 16 + fr;
        float gv = accg[i][j][r], uv = accu[i][j][r];
        float hv = (gv / (1.f + __expf(-gv))) * uv;
        if (routed) hv *= ewLds[wm + i * 16 + fq * 4 + r];  // LDS broadcast
        hp[(size_t)row * I_DIM + col] = f2bf(hv);
      }
}

// ---------------- down GEMM: 128x192 tile, BK=64 -----------------------------
// MODE 0: shared store. MODE 1: routed RMW out += v (h pre-scaled by w).
// MODE 2: fused shared+primary (two K-loops, one acc, single store).
// A: 2 passes (rows q, q+64); B: 3 passes (rows q, q+64, q+128).
#define DK_KLOOP(GA0, GA1, GB)                                              \
  for (int k0 = 0; k0 < I_DIM; k0 += 64) {                                  \
    gl16((GA0) + k0, (char*)Ab + wb);                                       \
    gl16((GA1) + k0, (char*)Ab + 8192 + wb);                                \
    gl16((GB) + k0, (char*)Bb + wb);                                        \
    gl16((GB) + 32768 + k0, (char*)Bb + 8192 + wb);                         \
    gl16((GB) + 65536 + k0, (char*)Bb + 16384 + wb);                        \
    __syncthreads();                                                        \
    _Pragma("unroll") for (int s = 0; s < 2; s++) {                         \
      short8 a[4], b2[3];                                                   \
      _Pragma("unroll") for (int i = 0; i < 4; i++) {                       \
        int r = wm + i * 16 + fr;                                           \
        a[i] = *(const short8*)&Ab[r * 64 + (((s << 2) + fq) ^ (r & 7)) * 8]; \
      }                                                                     \
      _Pragma("unroll") for (int j = 0; j < 3; j++) {                       \
        int r = wn + j * 16 + fr;                                           \
        b2[j] = *(const short8*)&Bb[r * 64 + (((s << 2) + fq) ^ (r & 7)) * 8]; \
      }                                                                     \
      _Pragma("unroll") for (int i = 0; i < 4; i++)                         \
        _Pragma("unroll") for (int j = 0; j < 3; j++)                       \
          acc[i][j] = __builtin_amdgcn_mfma_f32_16x16x32_bf16(a[i], b2[j],  \
                                                              acc[i][j], 0, 0, 0); \
    }                                                                       \
    __syncthreads();                                                        \
  }

template <int MODE>
__global__ __launch_bounds__(512, 2) void down_k(
    const unsigned short* __restrict__ hbuf, const unsigned short* __restrict__ hS,
    const unsigned short* __restrict__ wd, const unsigned short* __restrict__ wsd,
    float* __restrict__ out, const int* __restrict__ etok,
    const int* __restrict__ offs16, const int* __restrict__ pcnt16,
    const int* __restrict__ pinfo, int p, int merged, int mchunk) {
  int bid = blockIdx.x;
  int xcd = bid & 7, l = bid >> 3;
  int mb = xcd * mchunk + l / 3;
  int nb = l % 3;
  int nrows = (MODE == 0) ? T_TOK : pinfo[p];
  if (mb * 128 >= nrows) return;
  int row_lo = (MODE == 1 && p == 1) ? pinfo[0] : 0;
  int hrow_lo = (MODE == 1 && merged) ? row_lo : 0;
  __shared__ char lds[40960];  // A 16KB | B 24KB ; epilogue fp32 32x192 (24KB)
  unsigned short* Ab = (unsigned short*)lds;
  unsigned short* Bb = (unsigned short*)(lds + 16384);
  int t = threadIdx.x;
  int wv = t >> 6, lane = t & 63;
  int q = t >> 3;
  int sg8 = (t & 7) ^ (q & 7);
  int e = 0, tokA0 = 0, tokA1 = 0;
  if (MODE >= 1) {
    int g = row_lo + mb * 128 + q;
    int s = 0;
#pragma unroll
    for (int i = 0; i < 15; i++) s += (g >= offs16[i] + pcnt16[i]) ? 1 : 0;
    e = s & 7;
    if (MODE == 2) {
      int tk = etok[g];
      tokA0 = (tk < 0) ? 0 : tk;
      tk = etok[g + 64];
      tokA1 = (tk < 0) ? 0 : tk;
    }
  }
  const unsigned short* gaR = hbuf + (size_t)(hrow_lo + mb * 128 + q) * I_DIM + sg8 * 8;
  int n00 = nb * 192 + q;
  const unsigned short* gbR = wd + (size_t)e * WELEM + (size_t)n00 * I_DIM + sg8 * 8;
  int wb = wv * 1024;
  int fr = lane & 15, fq = lane >> 4;
  int wm = (wv >> 2) * 64, wn = (wv & 3) * 48;
  f32x4 acc[4][3] = {};
  if (MODE == 2) {
    // loop 1: shared expert (A = hS gathered by token, B = wsd)
    const unsigned short* gaS0 = hS + (size_t)tokA0 * I_DIM + sg8 * 8;
    const unsigned short* gaS1 = hS + (size_t)tokA1 * I_DIM + sg8 * 8;
    const unsigned short* gbS = wsd + (size_t)n00 * I_DIM + sg8 * 8;
    DK_KLOOP(gaS0, gaS1, gbS);
  }
  // main loop (routed for MODE 1/2, shared h for MODE 0); A rows sequential
  DK_KLOOP(gaR, gaR + 32768, gbR);
  // staged epilogue: 4 chunks of 32 rows x 192 cols fp32 (24 KB)
  float* st = (float*)lds;
#pragma unroll
  for (int c = 0; c < 4; c++) {
    __syncthreads();
    if ((wm == 64) == (c >= 2)) {
#pragma unroll
      for (int ii = 0; ii < 2; ii++) {
        int i = (c & 1) * 2 + ii;
#pragma unroll
        for (int j = 0; j < 3; j++)
#pragma unroll
          for (int r = 0; r < 4; r++)
            st[(ii * 16 + fq * 4 + r) * 192 + wn + j * 16 + fr] = acc[i][j][r];
      }
    }
    __syncthreads();
#pragma unroll
    for (int i2 = 0; i2 < 3; i2++) {
      int s = t + i2 * 512;
      int lr = s / 48, qq = s % 48;
      int mloc = mb * 128 + c * 32 + lr;
      int colv = nb * 192 + qq * 4;
      f4 v = *(f4*)&st[lr * 192 + qq * 4];
      if (MODE == 0) {
        *(f4*)&out[(size_t)mloc * H_DIM + colv] = v;
      } else {
        int g = row_lo + mloc;
        int tok = etok[g];
        if (tok >= 0) {
          float* op = &out[(size_t)tok * H_DIM + colv];
          if (MODE == 2) {
            *(f4*)op = v;          // first and only full write of this row
          } else {
            f4 o = *(f4*)op;
            o.x += v.x; o.y += v.y; o.z += v.z; o.w += v.w;
            *(f4*)op = o;
          }
        }
      }
    }
  }
}

// ================= host =======================================================

extern "C" void kernel_launch(void* const* d_in, const int* in_sizes, int n_in,
                              void* d_out, int out_size, void* d_ws, size_t ws_size,
                              hipStream_t stream) {
  const float* x = (const float*)d_in[0];
  const float* sgw = (const float*)d_in[1];
  const float* suw = (const float*)d_in[2];
  const float* sdw = (const float*)d_in[3];
  const float* rgw = (const float*)d_in[4];
  const float* ruw = (const float*)d_in[5];
  const float* rdw = (const float*)d_in[6];
  const float* rw = (const float*)d_in[7];
  const float* rb = (const float*)d_in[8];
  float* out = (float*)d_out;
  char* ws = (char*)d_ws;

  const size_t o_xb = 0;
  const size_t o_w = 37748736;
  const size_t w_sg = o_w;
  const size_t w_su = o_w + 589824;
  const size_t w_sd = o_w + 1179648;
  const size_t w_rg = o_w + 1769472;
  const size_t w_ru = o_w + 6488064;
  const size_t w_rd = o_w + 11206656;
  const size_t o_tki = o_w + 15925248;
  const size_t o_tkw = o_tki + 262144;
  const size_t o_meta = o_tkw + 262144;
  const size_t o_etok = o_meta + 8192;
  const size_t o_ew = o_etok + 270336;
  const size_t o_h = o_ew + 270336;                       // routed h: 67584 rows
  const size_t o_hS = o_h + (size_t)67584 * 1024;         // shared h: 32768 rows
  const size_t need_t2 = o_hS;                            // 123,953,152
  const size_t need_t3 = o_hS + (size_t)32768 * 1024;     // 157,507,584

  unsigned short* xb = (unsigned short*)(ws + o_xb);
  int* tki = (int*)(ws + o_tki);
  float* tkw = (float*)(ws + o_tkw);
  int* counts = (int*)(ws + o_meta);
  int* cursor = counts + 512;
  int* offs16 = counts + 1024;
  int* pcnt16 = counts + 1040;
  int* pinfo = counts + 1056;
  int* etok = (int*)(ws + o_etok);
  float* ew = (float*)(ws + o_ew);
  unsigned short* h = (unsigned short*)(ws + o_h);
  unsigned short* hS = (unsigned short*)(ws + o_hS);

  unsigned short* wsg = (unsigned short*)(ws + w_sg);
  unsigned short* wsu = (unsigned short*)(ws + w_su);
  unsigned short* wsd = (unsigned short*)(ws + w_sd);
  unsigned short* wrg = (unsigned short*)(ws + w_rg);
  unsigned short* wru = (unsigned short*)(ws + w_ru);
  unsigned short* wrd = (unsigned short*)(ws + w_rd);

  hipMemsetAsync(ws + o_meta, 0, 8192, stream);
  hipMemsetAsync(etok, 0xFF, 270336, stream);
  hipMemsetAsync(ew, 0, 270336, stream);   // pads read by gateup (w=0)

  prep_k<<<NB_RT + NB_CW, 256, 0, stream>>>(
      x, xb, rw, rb, tki, tkw, counts,
      sgw, suw, rgw, ruw, sdw, rdw, wsg, wsu, wrg, wru, wsd, wrd);
  scatter_k<<<128, 256, 0, stream>>>(tki, tkw, counts, cursor, etok, ew,
                                     offs16, pcnt16, pinfo);

  if (ws_size >= need_t3) {
    // tier 3: one gateup launch (shared->hS, routed merged->h, w folded);
    // fused shared+primary down (store), then secondary down (RMW).
    gateup_k<<<NB_GU_R + NB_GU_S, 512, 0, stream>>>(
        xb, wsg, wsu, wrg, wru, hS, h, etok, ew, offs16, pcnt16, pinfo,
        NB_GU_R, 0, 1, 66);
    down_k<2><<<792, 512, 0, stream>>>(h, hS, wrd, wsd, out, etok,
                                       offs16, pcnt16, pinfo, 0, 1, 33);
    down_k<1><<<792, 512, 0, stream>>>(h, nullptr, wrd, nullptr, out, etok,
                                       offs16, pcnt16, pinfo, 1, 1, 33);
  } else if (ws_size >= need_t2) {
    // tier 2: single h buffer, merged routed, separate shared down
    gateup_k<<<NB_GU_S, 512, 0, stream>>>(
        xb, wsg, wsu, wrg, wru, h, h, etok, ew, offs16, pcnt16, pinfo,
        0, 0, 1, 66);
    down_k<0><<<768, 512, 0, stream>>>(h, nullptr, wsd, nullptr, out, etok,
                                       offs16, pcnt16, pinfo, 0, 0, 32);
    gateup_k<<<NB_GU_R, 512, 0, stream>>>(
        xb, wsg, wsu, wrg, wru, h, h, etok, ew, offs16, pcnt16, pinfo,
        NB_GU_R, 0, 1, 66);
    down_k<1><<<792, 512, 0, stream>>>(h, nullptr, wrd, nullptr, out, etok,
                                       offs16, pcnt16, pinfo, 0, 1, 33);
    down_k<1><<<792, 512, 0, stream>>>(h, nullptr, wrd, nullptr, out, etok,
                                       offs16, pcnt16, pinfo, 1, 1, 33);
  } else {
    // tier 1: per-phase fallback (h phase-local)
    gateup_k<<<NB_GU_S, 512, 0, stream>>>(
        xb, wsg, wsu, wrg, wru, h, h, etok, ew, offs16, pcnt16, pinfo,
        0, 0, 0, 33);
    down_k<0><<<768, 512, 0, stream>>>(h, nullptr, wsd, nullptr, out, etok,
                                       offs16, pcnt16, pinfo, 0, 0, 32);
    for (int p = 0; p < 2; p++) {
      gateup_k<<<1056, 512, 0, stream>>>(
          xb, wsg, wsu, wrg, wru, h, h, etok, ew, offs16, pcnt16, pinfo,
          1056, p, 0, 33);
      down_k<1><<<792, 512, 0, stream>>>(h, nullptr, wrd, nullptr, out, etok,
                                         offs16, pcnt16, pinfo, p, 0, 33);
    }
  }
}

// Round 17
// 286.296 us; speedup vs baseline: 1.3376x; 1.0043x over previous
//
#include <hip/hip_runtime.h>
#include <stdint.h>

#define T_TOK 32768
#define H_DIM 576
#define I_DIM 512
#define NEXP 8
#define WELEM 294912  // 576*512 elements per expert weight matrix

#define NB_RT 512     // prep: router blocks (64 tokens each)
#define NB_CW 7776    // prep: weight-transpose blocks
#define NB_GU_R 2112  // routed gateup blocks (merged, 528 mb x 4 nb)
#define NB_GU_S 1024  // shared gateup blocks (256 mb x 4 nb)

typedef __attribute__((ext_vector_type(8))) short short8;
typedef __attribute__((ext_vector_type(4))) float f32x4;
typedef __attribute__((ext_vector_type(4))) float f4;
typedef __attribute__((ext_vector_type(4))) unsigned short u16x4;

__device__ __forceinline__ unsigned short f2bf(float f) {
  union { float f; unsigned u; } v; v.f = f;
  unsigned r = (v.u + 0x7fffu + ((v.u >> 16) & 1u)) >> 16;
  return (unsigned short)r;
}

__device__ __forceinline__ void gl16(const void* g, void* l) {
  __builtin_amdgcn_global_load_lds(
      (const __attribute__((address_space(1))) unsigned*)g,
      (__attribute__((address_space(3))) unsigned*)l, 16, 0, 0);
}

// ============ packed prep: router+cvt_x (512 blks) || weight transposes ======
__global__ __launch_bounds__(256) void prep_k(
    const float* __restrict__ x, unsigned short* __restrict__ xb,
    const float* __restrict__ rw, const float* __restrict__ rb,
    int* __restrict__ tki, float* __restrict__ tkw, int* __restrict__ counts,
    const float* __restrict__ sgw, const float* __restrict__ suw,
    const float* __restrict__ rgw, const float* __restrict__ ruw,
    const float* __restrict__ sdw, const float* __restrict__ rdw,
    unsigned short* __restrict__ wsg, unsigned short* __restrict__ wsu,
    unsigned short* __restrict__ wrg, unsigned short* __restrict__ wru,
    unsigned short* __restrict__ wsd, unsigned short* __restrict__ wrd) {
  __shared__ __align__(16) char smem[29312];
  int b = blockIdx.x, tid = threadIdx.x;
  if (b < NB_RT) {
    float* lrw = (float*)smem;                         // 18432 B
    float (*tile)[68] = (float(*)[68])(smem + 18432);  // 8704 B
    float (*red)[8] = (float(*)[8])(smem + 27136);     // 2048 B
    int* hist = (int*)(smem + 29184);                  // 64 B
    for (int i = tid; i < 1152; i += 256)
      *(f4*)&lrw[i * 4] = *(const f4*)&rw[i * 4];
    if (tid < 16) hist[tid] = 0;
    int t0 = b * 64;
    float acc[NEXP] = {};
    for (int c = 0; c < 18; c++) {
      __syncthreads();
#pragma unroll
      for (int k = 0; k < 2; k++) {
        int f = tid + k * 256;
        int rgrp = f >> 8, fl = f & 255;
        int tl2 = fl >> 2, seg = fl & 3;
        int h = rgrp * 288 + c * 16 + seg * 4;
        size_t gi = (size_t)(t0 + tl2) * H_DIM + h;
        f4 v = *(const f4*)(x + gi);
        u16x4 o;
        o.x = f2bf(v.x); o.y = f2bf(v.y); o.z = f2bf(v.z); o.w = f2bf(v.w);
        *(u16x4*)(xb + gi) = o;
        int row = rgrp * 16 + seg * 4;
        tile[row + 0][tl2] = v.x; tile[row + 1][tl2] = v.y;
        tile[row + 2][tl2] = v.z; tile[row + 3][tl2] = v.w;
      }
      __syncthreads();
      if (tid < 128) {
        int half = tid >> 6, tl = tid & 63;
        int hbase = half * 288 + c * 16;
        int rbase = half * 16;
#pragma unroll
        for (int hh = 0; hh < 16; hh++) {
          float xv = tile[rbase + hh][tl];
          f4 w0 = *(const f4*)&lrw[(hbase + hh) * 8];
          f4 w1 = *(const f4*)&lrw[(hbase + hh) * 8 + 4];
          acc[0] += xv * w0.x; acc[1] += xv * w0.y;
          acc[2] += xv * w0.z; acc[3] += xv * w0.w;
          acc[4] += xv * w1.x; acc[5] += xv * w1.y;
          acc[6] += xv * w1.z; acc[7] += xv * w1.w;
        }
      }
    }
    if (tid >= 64 && tid < 128) {
      int tl = tid & 63;
#pragma unroll
      for (int e = 0; e < NEXP; e++) red[tl][e] = acc[e];
    }
    __syncthreads();
    if (tid < 64) {
      int t = t0 + tid;
      float l[NEXP];
#pragma unroll
      for (int e = 0; e < NEXP; e++) l[e] = acc[e] + red[tid][e] + rb[e];
      int e0 = 0;
#pragma unroll
      for (int e = 1; e < NEXP; e++) if (l[e] > l[e0]) e0 = e;
      int e1 = -1;
#pragma unroll
      for (int e = 0; e < NEXP; e++) {
        if (e == e0) continue;
        if (e1 < 0 || l[e] > l[e1]) e1 = e;
      }
      float w0 = 1.f / (1.f + __expf(l[e1] - l[e0]));
      tki[t * 2] = e0; tki[t * 2 + 1] = e1;
      tkw[t * 2] = w0; tkw[t * 2 + 1] = 1.f - w0;
      atomicAdd(&hist[e0], 1);
      atomicAdd(&hist[8 + e1], 1);
    }
    __syncthreads();
    if (tid < 16) atomicAdd(&counts[tid * 32], hist[tid]);
  } else {
    float (*tile)[33] = (float(*)[33])smem;
    int b0 = b - NB_RT;
    const float* src; unsigned short* dst;
    int C, bx, by;
    if (b0 < 5184) {
      int z = b0 / 288, r = b0 % 288;
      bx = r & 15; by = r >> 4; C = 512;
      if (z == 0)      { src = sgw;                            dst = wsg; }
      else if (z == 1) { src = suw;                            dst = wsu; }
      else if (z < 10) { src = rgw + (size_t)(z - 2) * WELEM;  dst = wrg + (size_t)(z - 2) * WELEM; }
      else             { src = ruw + (size_t)(z - 10) * WELEM; dst = wru + (size_t)(z - 10) * WELEM; }
    } else {
      int b2 = b0 - 5184;
      int z = b2 / 288, r = b2 % 288;
      bx = r % 18; by = r / 18; C = 576;
      src = (z == 0) ? sdw : rdw + (size_t)(z - 1) * WELEM;
      dst = (z == 0) ? wsd : wrd + (size_t)(z - 1) * WELEM;
    }
    int R = 1088 - C;
    int tx = tid & 31, ty = tid >> 5;
    int r0 = by * 32, c0 = bx * 32;
    for (int i = ty; i < 32; i += 8)
      tile[i][tx] = src[(size_t)(r0 + i) * C + c0 + tx];
    __syncthreads();
    for (int i = ty; i < 32; i += 8)
      dst[(size_t)(c0 + i) * R + r0 + tx] = f2bf(tile[tx][i]);
  }
}

// ============ scatter with fused offsets scan ================================
__global__ __launch_bounds__(256) void scatter_k(
    const int* __restrict__ tki, const float* __restrict__ tkw,
    const int* __restrict__ counts, int* __restrict__ cursor /*stride 32*/,
    int* __restrict__ etok, float* __restrict__ ew,
    int* __restrict__ offs16g, int* __restrict__ pcnt16g,
    int* __restrict__ pinfog) {
  __shared__ int soffs[16], hist[16], base[16], lcur[16];
  int tid = threadIdx.x;
  if (tid == 0) {
    int o = 0, p0 = 0;
    for (int s = 0; s < 16; s++) {
      int c = counts[s * 32];
      int pc = (c + 127) & ~127;
      soffs[s] = o;
      if (blockIdx.x == 0) { offs16g[s] = o; pcnt16g[s] = pc; }
      o += pc;
      if (s == 7) p0 = o;
    }
    if (blockIdx.x == 0) { pinfog[0] = p0; pinfog[1] = o - p0; }
  }
  if (tid < 16) { hist[tid] = 0; lcur[tid] = 0; }
  __syncthreads();
  int t = blockIdx.x * 256 + tid;
  int s0 = tki[t * 2], s1 = 8 + tki[t * 2 + 1];
  atomicAdd(&hist[s0], 1);
  atomicAdd(&hist[s1], 1);
  __syncthreads();
  if (tid < 16) base[tid] = atomicAdd(&cursor[tid * 32], hist[tid]);
  __syncthreads();
#pragma unroll
  for (int k = 0; k < 2; k++) {
    int s = (k == 0) ? s0 : s1;
    int r = atomicAdd(&lcur[s], 1);
    int slot = soffs[s] + base[s] + r;
    etok[slot] = t;
    ew[slot] = tkw[t * 2 + k];
  }
}

// ---------------- fused gate/up GEMM + silu, BK=64 (r16 proven) --------------
__global__ __launch_bounds__(512, 2) void gateup_k(
    const unsigned short* __restrict__ xb,
    const unsigned short* __restrict__ wg_s, const unsigned short* __restrict__ wu_s,
    const unsigned short* __restrict__ wg_r, const unsigned short* __restrict__ wu_r,
    unsigned short* __restrict__ h_s, unsigned short* __restrict__ h_r,
    const int* __restrict__ etok, const float* __restrict__ ew,
    const int* __restrict__ offs16, const int* __restrict__ pcnt16,
    const int* __restrict__ pinfo,
    int nrg, int p, int merged, int mchunk_r) {
  int bid = blockIdx.x;
  bool routed = bid < nrg;
  int mb, nb;
  if (routed) {
    int xcd = bid & 7, l = bid >> 3;
    mb = xcd * mchunk_r + (l >> 2);
    nb = l & 3;
    int nrows = merged ? pinfo[0] + pinfo[1] : pinfo[p];
    if (mb * 128 >= nrows) return;
  } else {
    int b2 = bid - nrg;
    int xcd = b2 & 7, l = b2 >> 3;
    mb = xcd * 32 + (l >> 2);
    nb = l & 3;
  }
  __shared__ unsigned short As[128 * 64];
  __shared__ unsigned short Bg[128 * 64];
  __shared__ unsigned short Bu[128 * 64];
  __shared__ float ewLds[128];
  int t = threadIdx.x;
  int wv = t >> 6, lane = t & 63;
  int q = t >> 3;                    // staging row (pass 0), 0..63
  int sg8 = (t & 7) ^ (q & 7);       // pre-swizzled 16B slot
  int tok0, tok1;
  const unsigned short *wgp, *wup;
  unsigned short* hp;
  const float* ewp = nullptr;
  if (routed) {
    int rl = (!merged && p) ? pinfo[0] : 0;
    int g = rl + mb * 128 + q;
    int s = 0;
#pragma unroll
    for (int i = 0; i < 15; i++) s += (g >= offs16[i] + pcnt16[i]) ? 1 : 0;
    int e = s & 7;
    tok0 = etok[g];
    if (tok0 < 0) tok0 = 0;
    tok1 = etok[g + 64];
    if (tok1 < 0) tok1 = 0;
    wgp = wg_r + (size_t)e * WELEM;
    wup = wu_r + (size_t)e * WELEM;
    hp = h_r;
    ewp = ew + rl;
  } else {
    tok0 = mb * 128 + q;
    tok1 = tok0 + 64;
    wgp = wg_s;
    wup = wu_s;
    hp = h_s;
  }
  if (routed && t < 32) gl16(ewp + mb * 128 + t * 4, ewLds);
  const unsigned short* ga0 = xb + (size_t)tok0 * H_DIM + sg8 * 8;
  const unsigned short* ga1 = xb + (size_t)tok1 * H_DIM + sg8 * 8;
  int n0 = nb * 128 + q;
  const unsigned short* gg = wgp + (size_t)n0 * H_DIM + sg8 * 8;
  const unsigned short* gu = wup + (size_t)n0 * H_DIM + sg8 * 8;
  int wb = wv * 1024;
  int fr = lane & 15, fq = lane >> 4;
  int wm = (wv >> 2) * 64, wn = (wv & 3) * 32;
  f32x4 accg[4][2] = {};
  f32x4 accu[4][2] = {};
  for (int k0 = 0; k0 < H_DIM; k0 += 64) {
    gl16(ga0 + k0, (char*)As + wb);
    gl16(ga1 + k0, (char*)As + 8192 + wb);
    gl16(gg + k0, (char*)Bg + wb);
    gl16(gg + 36864 + k0, (char*)Bg + 8192 + wb);   // +64 rows * 576
    gl16(gu + k0, (char*)Bu + wb);
    gl16(gu + 36864 + k0, (char*)Bu + 8192 + wb);
    __syncthreads();
#pragma unroll
    for (int s = 0; s < 2; s++) {
      short8 a[4], g2[2], u2[2];
#pragma unroll
      for (int i = 0; i < 4; i++) {
        int r = wm + i * 16 + fr;
        a[i] = *(const short8*)&As[r * 64 + (((s << 2) + fq) ^ (r & 7)) * 8];
      }
#pragma unroll
      for (int j = 0; j < 2; j++) {
        int r = wn + j * 16 + fr;
        int sw = (((s << 2) + fq) ^ (r & 7)) * 8;
        g2[j] = *(const short8*)&Bg[r * 64 + sw];
        u2[j] = *(const short8*)&Bu[r * 64 + sw];
      }
#pragma unroll
      for (int i = 0; i < 4; i++)
#pragma unroll
        for (int j = 0; j < 2; j++) {
          accg[i][j] = __builtin_amdgcn_mfma_f32_16x16x32_bf16(a[i], g2[j], accg[i][j], 0, 0, 0);
          accu[i][j] = __builtin_amdgcn_mfma_f32_16x16x32_bf16(a[i], u2[j], accu[i][j], 0, 0, 0);
        }
    }
    __syncthreads();
  }
#pragma unroll
  for (int i = 0; i < 4; i++)
#pragma unroll
    for (int j = 0; j < 2; j++)
#pragma unroll
      for (int r = 0; r < 4; r++) {
        int row = mb * 128 + wm + i * 16 + fq * 4 + r;
        int col = nb * 128 + wn + j * 16 + fr;
        float gv = accg[i][j][r], uv = accu[i][j][r];
        float hv = (gv / (1.f + __expf(-gv))) * uv;
        if (routed) hv *= ewLds[wm + i * 16 + fq * 4 + r];  // LDS broadcast
        hp[(size_t)row * I_DIM + col] = f2bf(hv);
      }
}

// ---------------- down GEMM: 128x192 tile, BK=128 ----------------------------
// BK 64->128: barrier drains halve; LDS 80KB (2 blocks/CU by LDS = reg cap, so
// occupancy unchanged). Swizzle for 256B rows: staged slot (t&15)^((t>>4)&15)
// (pass-invariant, +32 rows = 0 mod 16); read slot (s*4+fq)^(r&15) -> 16-lane
// fragment hits 16 distinct 16B slots = 2-way bank alias (free). MFMA k-order
// globally ascending, bit-identical to BK=64.
// MODE 0: shared store. MODE 1: routed RMW. MODE 2: fused shared+primary.
#define DK_KLOOP(GA0, GA1, GA2, GA3, GB)                                    \
  for (int k0 = 0; k0 < I_DIM; k0 += 128) {                                 \
    gl16((GA0) + k0, (char*)Ab + wb);                                       \
    gl16((GA1) + k0, (char*)Ab + 8192 + wb);                                \
    gl16((GA2) + k0, (char*)Ab + 16384 + wb);                               \
    gl16((GA3) + k0, (char*)Ab + 24576 + wb);                               \
    gl16((GB) + k0, (char*)Bb + wb);                                        \
    gl16((GB) + 16384 + k0, (char*)Bb + 8192 + wb);                         \
    gl16((GB) + 32768 + k0, (char*)Bb + 16384 + wb);                        \
    gl16((GB) + 49152 + k0, (char*)Bb + 24576 + wb);                        \
    gl16((GB) + 65536 + k0, (char*)Bb + 32768 + wb);                        \
    gl16((GB) + 81920 + k0, (char*)Bb + 40960 + wb);                        \
    __syncthreads();                                                        \
    _Pragma("unroll") for (int s = 0; s < 4; s++) {                         \
      short8 a[4], b2[3];                                                   \
      _Pragma("unroll") for (int i = 0; i < 4; i++) {                       \
        int r = wm + i * 16 + fr;                                           \
        a[i] = *(const short8*)&Ab[r * 128 + (((s << 2) + fq) ^ (r & 15)) * 8]; \
      }                                                                     \
      _Pragma("unroll") for (int j = 0; j < 3; j++) {                       \
        int r = wn + j * 16 + fr;                                           \
        b2[j] = *(const short8*)&Bb[r * 128 + (((s << 2) + fq) ^ (r & 15)) * 8]; \
      }                                                                     \
      _Pragma("unroll") for (int i = 0; i < 4; i++)                         \
        _Pragma("unroll") for (int j = 0; j < 3; j++)                       \
          acc[i][j] = __builtin_amdgcn_mfma_f32_16x16x32_bf16(a[i], b2[j],  \
                                                              acc[i][j], 0, 0, 0); \
    }                                                                       \
    __syncthreads();                                                        \
  }

template <int MODE>
__global__ __launch_bounds__(512, 2) void down_k(
    const unsigned short* __restrict__ hbuf, const unsigned short* __restrict__ hS,
    const unsigned short* __restrict__ wd, const unsigned short* __restrict__ wsd,
    float* __restrict__ out, const int* __restrict__ etok,
    const int* __restrict__ offs16, const int* __restrict__ pcnt16,
    const int* __restrict__ pinfo, int p, int merged, int mchunk) {
  int bid = blockIdx.x;
  int xcd = bid & 7, l = bid >> 3;
  int mb = xcd * mchunk + l / 3;
  int nb = l % 3;
  int nrows = (MODE == 0) ? T_TOK : pinfo[p];
  if (mb * 128 >= nrows) return;
  int row_lo = (MODE == 1 && p == 1) ? pinfo[0] : 0;
  int hrow_lo = (MODE == 1 && merged) ? row_lo : 0;
  __shared__ char lds[81920];  // A 32KB | B 48KB ; epilogue fp32 32x192 (24KB)
  unsigned short* Ab = (unsigned short*)lds;
  unsigned short* Bb = (unsigned short*)(lds + 32768);
  int t = threadIdx.x;
  int wv = t >> 6, lane = t & 63;
  int q16 = t >> 4;                   // staging row within pass, 0..31
  int sg16 = (t & 15) ^ (q16 & 15);   // pre-swizzled 16B slot
  int e = 0;
  int tokA[4] = {};
  if (MODE >= 1) {
    int g = row_lo + mb * 128 + q16;
    int s = 0;
#pragma unroll
    for (int i = 0; i < 15; i++) s += (g >= offs16[i] + pcnt16[i]) ? 1 : 0;
    e = s & 7;
    if (MODE == 2) {
#pragma unroll
      for (int pp = 0; pp < 4; pp++) {
        int tk = etok[g + pp * 32];
        tokA[pp] = (tk < 0) ? 0 : tk;
      }
    }
  }
  const unsigned short* gaR = hbuf + (size_t)(hrow_lo + mb * 128 + q16) * I_DIM + sg16 * 8;
  int n00 = nb * 192 + q16;
  const unsigned short* gbR = wd + (size_t)e * WELEM + (size_t)n00 * I_DIM + sg16 * 8;
  int wb = wv * 1024;
  int fr = lane & 15, fq = lane >> 4;
  int wm = (wv >> 2) * 64, wn = (wv & 3) * 48;
  f32x4 acc[4][3] = {};
  if (MODE == 2) {
    // loop 1: shared expert (A = hS gathered by token per pass, B = wsd)
    const unsigned short* gaS0 = hS + (size_t)tokA[0] * I_DIM + sg16 * 8;
    const unsigned short* gaS1 = hS + (size_t)tokA[1] * I_DIM + sg16 * 8;
    const unsigned short* gaS2 = hS + (size_t)tokA[2] * I_DIM + sg16 * 8;
    const unsigned short* gaS3 = hS + (size_t)tokA[3] * I_DIM + sg16 * 8;
    const unsigned short* gbS = wsd + (size_t)n00 * I_DIM + sg16 * 8;
    DK_KLOOP(gaS0, gaS1, gaS2, gaS3, gbS);
  }
  // main loop (routed for MODE 1/2, shared h for MODE 0); A rows sequential
  DK_KLOOP(gaR, gaR + 16384, gaR + 32768, gaR + 49152, gbR);
  // staged epilogue: 4 chunks of 32 rows x 192 cols fp32 (24 KB)
  float* st = (float*)lds;
#pragma unroll
  for (int c = 0; c < 4; c++) {
    __syncthreads();
    if ((wm == 64) == (c >= 2)) {
#pragma unroll
      for (int ii = 0; ii < 2; ii++) {
        int i = (c & 1) * 2 + ii;
#pragma unroll
        for (int j = 0; j < 3; j++)
#pragma unroll
          for (int r = 0; r < 4; r++)
            st[(ii * 16 + fq * 4 + r) * 192 + wn + j * 16 + fr] = acc[i][j][r];
      }
    }
    __syncthreads();
#pragma unroll
    for (int i2 = 0; i2 < 3; i2++) {
      int s = t + i2 * 512;
      int lr = s / 48, qq = s % 48;
      int mloc = mb * 128 + c * 32 + lr;
      int colv = nb * 192 + qq * 4;
      f4 v = *(f4*)&st[lr * 192 + qq * 4];
      if (MODE == 0) {
        *(f4*)&out[(size_t)mloc * H_DIM + colv] = v;
      } else {
        int g = row_lo + mloc;
        int tok = etok[g];
        if (tok >= 0) {
          float* op = &out[(size_t)tok * H_DIM + colv];
          if (MODE == 2) {
            *(f4*)op = v;          // first and only full write of this row
          } else {
            f4 o = *(f4*)op;
            o.x += v.x; o.y += v.y; o.z += v.z; o.w += v.w;
            *(f4*)op = o;
          }
        }
      }
    }
  }
}

// ================= host =======================================================

extern "C" void kernel_launch(void* const* d_in, const int* in_sizes, int n_in,
                              void* d_out, int out_size, void* d_ws, size_t ws_size,
                              hipStream_t stream) {
  const float* x = (const float*)d_in[0];
  const float* sgw = (const float*)d_in[1];
  const float* suw = (const float*)d_in[2];
  const float* sdw = (const float*)d_in[3];
  const float* rgw = (const float*)d_in[4];
  const float* ruw = (const float*)d_in[5];
  const float* rdw = (const float*)d_in[6];
  const float* rw = (const float*)d_in[7];
  const float* rb = (const float*)d_in[8];
  float* out = (float*)d_out;
  char* ws = (char*)d_ws;

  const size_t o_xb = 0;
  const size_t o_w = 37748736;
  const size_t w_sg = o_w;
  const size_t w_su = o_w + 589824;
  const size_t w_sd = o_w + 1179648;
  const size_t w_rg = o_w + 1769472;
  const size_t w_ru = o_w + 6488064;
  const size_t w_rd = o_w + 11206656;
  const size_t o_tki = o_w + 15925248;
  const size_t o_tkw = o_tki + 262144;
  const size_t o_meta = o_tkw + 262144;
  const size_t o_etok = o_meta + 8192;
  const size_t o_ew = o_etok + 270336;
  const size_t o_h = o_ew + 270336;                       // routed h: 67584 rows
  const size_t o_hS = o_h + (size_t)67584 * 1024;         // shared h: 32768 rows
  const size_t need_t2 = o_hS;                            // 123,953,152
  const size_t need_t3 = o_hS + (size_t)32768 * 1024;     // 157,507,584

  unsigned short* xb = (unsigned short*)(ws + o_xb);
  int* tki = (int*)(ws + o_tki);
  float* tkw = (float*)(ws + o_tkw);
  int* counts = (int*)(ws + o_meta);
  int* cursor = counts + 512;
  int* offs16 = counts + 1024;
  int* pcnt16 = counts + 1040;
  int* pinfo = counts + 1056;
  int* etok = (int*)(ws + o_etok);
  float* ew = (float*)(ws + o_ew);
  unsigned short* h = (unsigned short*)(ws + o_h);
  unsigned short* hS = (unsigned short*)(ws + o_hS);

  unsigned short* wsg = (unsigned short*)(ws + w_sg);
  unsigned short* wsu = (unsigned short*)(ws + w_su);
  unsigned short* wsd = (unsigned short*)(ws + w_sd);
  unsigned short* wrg = (unsigned short*)(ws + w_rg);
  unsigned short* wru = (unsigned short*)(ws + w_ru);
  unsigned short* wrd = (unsigned short*)(ws + w_rd);

  hipMemsetAsync(ws + o_meta, 0, 8192, stream);
  hipMemsetAsync(etok, 0xFF, 270336, stream);
  hipMemsetAsync(ew, 0, 270336, stream);   // pads read by gateup (w=0)

  prep_k<<<NB_RT + NB_CW, 256, 0, stream>>>(
      x, xb, rw, rb, tki, tkw, counts,
      sgw, suw, rgw, ruw, sdw, rdw, wsg, wsu, wrg, wru, wsd, wrd);
  scatter_k<<<128, 256, 0, stream>>>(tki, tkw, counts, cursor, etok, ew,
                                     offs16, pcnt16, pinfo);

  if (ws_size >= need_t3) {
    // tier 3: one gateup launch (shared->hS, routed merged->h, w folded);
    // fused shared+primary down (store), then secondary down (RMW).
    gateup_k<<<NB_GU_R + NB_GU_S, 512, 0, stream>>>(
        xb, wsg, wsu, wrg, wru, hS, h, etok, ew, offs16, pcnt16, pinfo,
        NB_GU_R, 0, 1, 66);
    down_k<2><<<792, 512, 0, stream>>>(h, hS, wrd, wsd, out, etok,
                                       offs16, pcnt16, pinfo, 0, 1, 33);
    down_k<1><<<792, 512, 0, stream>>>(h, nullptr, wrd, nullptr, out, etok,
                                       offs16, pcnt16, pinfo, 1, 1, 33);
  } else if (ws_size >= need_t2) {
    // tier 2: single h buffer, merged routed, separate shared down
    gateup_k<<<NB_GU_S, 512, 0, stream>>>(
        xb, wsg, wsu, wrg, wru, h, h, etok, ew, offs16, pcnt16, pinfo,
        0, 0, 1, 66);
    down_k<0><<<768, 512, 0, stream>>>(h, nullptr, wsd, nullptr, out, etok,
                                       offs16, pcnt16, pinfo, 0, 0, 32);
    gateup_k<<<NB_GU_R, 512, 0, stream>>>(
        xb, wsg, wsu, wrg, wru, h, h, etok, ew, offs16, pcnt16, pinfo,
        NB_GU_R, 0, 1, 66);
    down_k<1><<<792, 512, 0, stream>>>(h, nullptr, wrd, nullptr, out, etok,
                                       offs16, pcnt16, pinfo, 0, 1, 33);
    down_k<1><<<792, 512, 0, stream>>>(h, nullptr, wrd, nullptr, out, etok,
                                       offs16, pcnt16, pinfo, 1, 1, 33);
  } else {
    // tier 1: per-phase fallback (h phase-local)
    gateup_k<<<NB_GU_S, 512, 0, stream>>>(
        xb, wsg, wsu, wrg, wru, h, h, etok, ew, offs16, pcnt16, pinfo,
        0, 0, 0, 33);
    down_k<0><<<768, 512, 0, stream>>>(h, nullptr, wsd, nullptr, out, etok,
                                       offs16, pcnt16, pinfo, 0, 0, 32);
    for (int p = 0; p < 2; p++) {
      gateup_k<<<1056, 512, 0, stream>>>(
          xb, wsg, wsu, wrg, wru, h, h, etok, ew, offs16, pcnt16, pinfo,
          1056, p, 0, 33);
      down_k<1><<<792, 512, 0, stream>>>(h, nullptr, wrd, nullptr, out, etok,
                                         offs16, pcnt16, pinfo, p, 0, 33);
    }
  }
}